// Round 1
// baseline (3014.278 us; speedup 1.0000x reference)
//
#include <hip/hip_runtime.h>
#include <hip/hip_bf16.h>
#include <math.h>

#define N_NODES 100000
#define N_EDGES 1600000
#define DIN 128
#define DH 256
#define DOUT 40
#define BN_EPS 1e-5f
#define STATS_BLOCKS 512

// ---------------------------------------------------------------- CSR build

__global__ void k_count(const int* __restrict__ row, int* __restrict__ cnt) {
    int e = blockIdx.x * blockDim.x + threadIdx.x;
    if (e < N_EDGES) atomicAdd(&cnt[row[e]], 1);
}

__global__ void k_dinv(const int* __restrict__ cnt, float* __restrict__ dinv) {
    int i = blockIdx.x * blockDim.x + threadIdx.x;
    if (i < N_NODES) dinv[i] = rsqrtf((float)(cnt[i] + 1));
}

// exclusive scan of (cnt[i]+1) over n elements, single block of 1024 threads
__global__ __launch_bounds__(1024) void k_scan(const int* __restrict__ cnt,
                                               int* __restrict__ rowptr, int n) {
    __shared__ int sdata[1024];
    __shared__ int carry_s;
    if (threadIdx.x == 0) carry_s = 0;
    __syncthreads();
    for (int base = 0; base < n; base += 1024) {
        int i = base + threadIdx.x;
        int v = (i < n) ? (cnt[i] + 1) : 0;
        sdata[threadIdx.x] = v;
        __syncthreads();
        for (int off = 1; off < 1024; off <<= 1) {
            int t = (threadIdx.x >= off) ? sdata[threadIdx.x - off] : 0;
            __syncthreads();
            sdata[threadIdx.x] += t;
            __syncthreads();
        }
        int incl = sdata[threadIdx.x];
        int carry = carry_s;
        if (i < n) rowptr[i] = carry + incl - v;
        __syncthreads();
        if (threadIdx.x == 1023) carry_s += sdata[1023];
        __syncthreads();
    }
    if (threadIdx.x == 0) rowptr[n] = carry_s;
}

__global__ void k_scatter(const int* __restrict__ row, const int* __restrict__ col,
                          const int* __restrict__ rowptr, int* __restrict__ fill,
                          int* __restrict__ colidx) {
    int e = blockIdx.x * blockDim.x + threadIdx.x;
    if (e >= N_EDGES) return;
    int r = row[e];
    int pos = rowptr[r] + atomicAdd(&fill[r], 1);
    colidx[pos] = col[e];
}

__global__ void k_selfloop(const int* __restrict__ rowptr, int* __restrict__ colidx) {
    int i = blockIdx.x * blockDim.x + threadIdx.x;
    if (i < N_NODES) colidx[rowptr[i + 1] - 1] = i;
}

// ---------------------------------------------------------------- GEMM
// C[m][n] = dinv[m] * sum_k act(A[m][k]) * W[k][n]
// act = BN? max(0, A*scale[k]+shift[k]) : identity

template <bool BN>
__global__ __launch_bounds__(256) void k_gemm(
    const float* __restrict__ A, const float* __restrict__ W,
    float* __restrict__ C, const float* __restrict__ dinv,
    const float* __restrict__ scale, const float* __restrict__ shift,
    int M, int K, int Nc) {
    const int bm = blockIdx.x * 64;
    const int bn = blockIdx.y * 64;
    __shared__ float As[16][64 + 1];
    __shared__ float Bs[16][64 + 1];
    const int t = threadIdx.x;
    const int tx = t & 15, ty = t >> 4;
    float acc[4][4] = {};
    for (int k0 = 0; k0 < K; k0 += 16) {
#pragma unroll
        for (int i = 0; i < 4; i++) {
            int l = t + i * 256;  // 0..1023 over 64x16 tile
            int r = l >> 4, k = l & 15;
            int gm = bm + r, gk = k0 + k;
            float v = 0.f;
            if (gm < M) v = A[(size_t)gm * K + gk];
            if (BN) v = fmaxf(fmaf(v, scale[gk], shift[gk]), 0.f);
            As[k][r] = v;
        }
#pragma unroll
        for (int i = 0; i < 4; i++) {
            int l = t + i * 256;  // 0..1023 over 16x64 tile
            int kk = l >> 6, nn = l & 63;
            int gk = k0 + kk, gn = bn + nn;
            float v = 0.f;
            if (gn < Nc) v = W[(size_t)gk * Nc + gn];
            Bs[kk][nn] = v;
        }
        __syncthreads();
#pragma unroll
        for (int kk = 0; kk < 16; kk++) {
            float a[4], b[4];
#pragma unroll
            for (int i = 0; i < 4; i++) a[i] = As[kk][ty * 4 + i];
#pragma unroll
            for (int j = 0; j < 4; j++) b[j] = Bs[kk][tx * 4 + j];
#pragma unroll
            for (int i = 0; i < 4; i++)
#pragma unroll
                for (int j = 0; j < 4; j++)
                    acc[i][j] = fmaf(a[i], b[j], acc[i][j]);
        }
        __syncthreads();
    }
#pragma unroll
    for (int i = 0; i < 4; i++) {
        int gm = bm + ty * 4 + i;
        if (gm >= M) continue;
        float d = dinv[gm];
#pragma unroll
        for (int j = 0; j < 4; j++) {
            int gn = bn + tx * 4 + j;
            if (gn < Nc) C[(size_t)gm * Nc + gn] = acc[i][j] * d;
        }
    }
}

// ---------------------------------------------------------------- aggregation
// one wave per node, 4 floats per lane (DH=256)

__global__ __launch_bounds__(256) void k_aggregate(
    const float* __restrict__ hs, const int* __restrict__ rowptr,
    const int* __restrict__ colidx, const float* __restrict__ dinv,
    const float* __restrict__ bias, float* __restrict__ out) {
    int gid = blockIdx.x * blockDim.x + threadIdx.x;
    int node = gid >> 6;
    int lane = gid & 63;
    if (node >= N_NODES) return;
    int s = rowptr[node], e = rowptr[node + 1];
    int fo = lane * 4;
    float4 acc = make_float4(0.f, 0.f, 0.f, 0.f);
    for (int i = s; i < e; i++) {
        int c = colidx[i];
        const float4 v = *(const float4*)(hs + (size_t)c * DH + fo);
        acc.x += v.x; acc.y += v.y; acc.z += v.z; acc.w += v.w;
    }
    float d = dinv[node];
    const float4 b = *(const float4*)(bias + fo);
    float4 r;
    r.x = fmaf(acc.x, d, b.x);
    r.y = fmaf(acc.y, d, b.y);
    r.z = fmaf(acc.z, d, b.z);
    r.w = fmaf(acc.w, d, b.w);
    *(float4*)(out + (size_t)node * DH + fo) = r;
}

// ---------------------------------------------------------------- BN stats

__global__ __launch_bounds__(256) void k_bnstats(const float* __restrict__ o,
                                                 float* __restrict__ psum,
                                                 float* __restrict__ psq) {
    int col = threadIdx.x;
    float s = 0.f, ss = 0.f;
    for (int r = blockIdx.x; r < N_NODES; r += gridDim.x) {
        float v = o[(size_t)r * DH + col];
        s += v;
        ss = fmaf(v, v, ss);
    }
    psum[(size_t)blockIdx.x * DH + col] = s;
    psq[(size_t)blockIdx.x * DH + col] = ss;
}

__global__ __launch_bounds__(256) void k_bnfinal(
    const float* __restrict__ psum, const float* __restrict__ psq,
    const float* __restrict__ gamma, const float* __restrict__ beta,
    float* __restrict__ scale, float* __restrict__ shift) {
    int c = threadIdx.x;
    float s = 0.f, ss = 0.f;
    for (int b = 0; b < STATS_BLOCKS; b++) {
        s += psum[(size_t)b * DH + c];
        ss += psq[(size_t)b * DH + c];
    }
    float mu = s / (float)N_NODES;
    float var = ss / (float)N_NODES - mu * mu;
    float rs = rsqrtf(var + BN_EPS);
    float sc = gamma[c] * rs;
    scale[c] = sc;
    shift[c] = beta[c] - mu * sc;
}

// ---------------------------------------------------------------- final layer

__global__ __launch_bounds__(256) void k_agg_softmax(
    const float* __restrict__ hs, const int* __restrict__ rowptr,
    const int* __restrict__ colidx, const float* __restrict__ dinv,
    const float* __restrict__ bias, float* __restrict__ out) {
    int gid = blockIdx.x * blockDim.x + threadIdx.x;
    int node = gid >> 6;
    int lane = gid & 63;
    if (node >= N_NODES) return;
    int s = rowptr[node], e = rowptr[node + 1];
    float acc = 0.f;
    if (lane < DOUT) {
        for (int i = s; i < e; i++) {
            int c = colidx[i];
            acc += hs[(size_t)c * DOUT + lane];
        }
        acc = fmaf(acc, dinv[node], bias[lane]);
    }
    float v = (lane < DOUT) ? acc : -INFINITY;
    float m = v;
#pragma unroll
    for (int off = 32; off; off >>= 1) m = fmaxf(m, __shfl_xor(m, off));
    float ex = (lane < DOUT) ? expf(acc - m) : 0.f;
    float sum = ex;
#pragma unroll
    for (int off = 32; off; off >>= 1) sum += __shfl_xor(sum, off);
    if (lane < DOUT) out[(size_t)node * DOUT + lane] = acc - m - logf(sum);
}

// ---------------------------------------------------------------- launch

static inline size_t align_up(size_t x, size_t a) { return (x + a - 1) & ~(a - 1); }

extern "C" void kernel_launch(void* const* d_in, const int* in_sizes, int n_in,
                              void* d_out, int out_size, void* d_ws, size_t ws_size,
                              hipStream_t stream) {
    const float* x     = (const float*)d_in[0];   // [N, 128]
    const float* W0    = (const float*)d_in[1];   // [128, 256]
    const float* b0    = (const float*)d_in[2];   // [256]
    const float* Wh    = (const float*)d_in[3];   // [3, 256, 256]
    const float* bh    = (const float*)d_in[4];   // [3, 256]
    const float* gamma = (const float*)d_in[5];   // [4, 256]
    const float* beta  = (const float*)d_in[6];   // [4, 256]
    const float* Wl    = (const float*)d_in[7];   // [256, 40]
    const float* bl    = (const float*)d_in[8];   // [40]
    const int* ei      = (const int*)d_in[9];     // [2, E]
    const int* row = ei;
    const int* col = ei + N_EDGES;
    float* out = (float*)d_out;

    // workspace layout
    char* ws = (char*)d_ws;
    size_t off = 0;
    const size_t NB = (size_t)N_NODES * DH * sizeof(float);  // 102.4 MB
    float* bufA = (float*)(ws + off); off = align_up(off + NB, 256);
    float* bufB = (float*)(ws + off); off = align_up(off + NB, 256);
    int* colidx = (int*)(ws + off);  off = align_up(off + (size_t)(N_EDGES + N_NODES) * 4, 256);
    int* cnt    = (int*)(ws + off);  off = align_up(off + (size_t)N_NODES * 4, 256);
    int* fill   = (int*)(ws + off);  off = align_up(off + (size_t)N_NODES * 4, 256);
    int* rowptr = (int*)(ws + off);  off = align_up(off + (size_t)(N_NODES + 1) * 4, 256);
    float* dinv = (float*)(ws + off); off = align_up(off + (size_t)N_NODES * 4, 256);
    float* psum = (float*)(ws + off); off = align_up(off + (size_t)STATS_BLOCKS * DH * 4, 256);
    float* psq  = (float*)(ws + off); off = align_up(off + (size_t)STATS_BLOCKS * DH * 4, 256);
    float* scale = (float*)(ws + off); off = align_up(off + DH * 4, 256);
    float* shift = (float*)(ws + off); off = align_up(off + DH * 4, 256);
    (void)ws_size; (void)n_in; (void)in_sizes; (void)out_size;

    hipMemsetAsync(cnt, 0, (size_t)N_NODES * 4, stream);
    hipMemsetAsync(fill, 0, (size_t)N_NODES * 4, stream);

    const int EB = (N_EDGES + 255) / 256;
    const int NBK = (N_NODES + 255) / 256;
    k_count<<<EB, 256, 0, stream>>>(row, cnt);
    k_dinv<<<NBK, 256, 0, stream>>>(cnt, dinv);
    k_scan<<<1, 1024, 0, stream>>>(cnt, rowptr, N_NODES);
    k_scatter<<<EB, 256, 0, stream>>>(row, col, rowptr, fill, colidx);
    k_selfloop<<<NBK, 256, 0, stream>>>(rowptr, colidx);

    const dim3 gemm_grid((N_NODES + 63) / 64, DH / 64);
    const dim3 gemm_grid_last((N_NODES + 63) / 64, 1);
    const int agg_blocks = (N_NODES * 64 + 255) / 256;

    // Layer 0: h = x @ W0 (no BN on input)
    k_gemm<false><<<gemm_grid, 256, 0, stream>>>(x, W0, bufA, dinv, nullptr, nullptr,
                                                 N_NODES, DIN, DH);
    k_aggregate<<<agg_blocks, 256, 0, stream>>>(bufA, rowptr, colidx, dinv, b0, bufB);
    k_bnstats<<<STATS_BLOCKS, 256, 0, stream>>>(bufB, psum, psq);
    k_bnfinal<<<1, 256, 0, stream>>>(psum, psq, gamma, beta, scale, shift);

    // Layers 1..3
    for (int i = 0; i < 3; i++) {
        k_gemm<true><<<gemm_grid, 256, 0, stream>>>(bufB, Wh + (size_t)i * DH * DH, bufA,
                                                    dinv, scale, shift, N_NODES, DH, DH);
        k_aggregate<<<agg_blocks, 256, 0, stream>>>(bufA, rowptr, colidx, dinv,
                                                    bh + (size_t)i * DH, bufB);
        k_bnstats<<<STATS_BLOCKS, 256, 0, stream>>>(bufB, psum, psq);
        k_bnfinal<<<1, 256, 0, stream>>>(psum, psq, gamma + (size_t)(i + 1) * DH,
                                         beta + (size_t)(i + 1) * DH, scale, shift);
    }

    // Layer 4: -> DOUT, then fused aggregate + bias + log_softmax
    k_gemm<true><<<gemm_grid_last, 256, 0, stream>>>(bufB, Wl, bufA, dinv, scale, shift,
                                                     N_NODES, DH, DOUT);
    k_agg_softmax<<<agg_blocks, 256, 0, stream>>>(bufA, rowptr, colidx, dinv, bl, out);
}

// Round 2
// 1906.278 us; speedup vs baseline: 1.5812x; 1.5812x over previous
//
#include <hip/hip_runtime.h>
#include <hip/hip_bf16.h>
#include <math.h>
#include <stdint.h>

#define N_NODES 100000
#define N_EDGES 1600000
#define DIN 128
#define DH 256
#define DOUT 40
#define BN_EPS 1e-5f
#define STATS_BLOCKS 512

typedef __attribute__((ext_vector_type(8))) short short8;
typedef __attribute__((ext_vector_type(4))) short short4v;
typedef __attribute__((ext_vector_type(4))) float floatx4;

__device__ __forceinline__ short f2bf(float f) {
    uint32_t u = __float_as_uint(f);
    uint32_t r = u + 0x7FFF + ((u >> 16) & 1);   // RNE
    return (short)(r >> 16);
}
__device__ __forceinline__ float bf_lo(uint32_t u) { return __uint_as_float(u << 16); }
__device__ __forceinline__ float bf_hi(uint32_t u) { return __uint_as_float(u & 0xFFFF0000u); }

// ---------------------------------------------------------------- CSR build

__global__ void k_count(const int* __restrict__ row, int* __restrict__ cnt) {
    int e = blockIdx.x * blockDim.x + threadIdx.x;
    if (e < N_EDGES) atomicAdd(&cnt[row[e]], 1);
}

__global__ void k_dinv(const int* __restrict__ cnt, float* __restrict__ dinv) {
    int i = blockIdx.x * blockDim.x + threadIdx.x;
    if (i < N_NODES) dinv[i] = rsqrtf((float)(cnt[i] + 1));
}

__global__ __launch_bounds__(1024) void k_scan(const int* __restrict__ cnt,
                                               int* __restrict__ rowptr, int n) {
    __shared__ int sdata[1024];
    __shared__ int carry_s;
    if (threadIdx.x == 0) carry_s = 0;
    __syncthreads();
    for (int base = 0; base < n; base += 1024) {
        int i = base + threadIdx.x;
        int v = (i < n) ? (cnt[i] + 1) : 0;
        sdata[threadIdx.x] = v;
        __syncthreads();
        for (int off = 1; off < 1024; off <<= 1) {
            int t = (threadIdx.x >= off) ? sdata[threadIdx.x - off] : 0;
            __syncthreads();
            sdata[threadIdx.x] += t;
            __syncthreads();
        }
        int incl = sdata[threadIdx.x];
        int carry = carry_s;
        if (i < n) rowptr[i] = carry + incl - v;
        __syncthreads();
        if (threadIdx.x == 1023) carry_s += sdata[1023];
        __syncthreads();
    }
    if (threadIdx.x == 0) rowptr[n] = carry_s;
}

__global__ void k_scatter(const int* __restrict__ row, const int* __restrict__ col,
                          const int* __restrict__ rowptr, int* __restrict__ fill,
                          int* __restrict__ colidx) {
    int e = blockIdx.x * blockDim.x + threadIdx.x;
    if (e >= N_EDGES) return;
    int r = row[e];
    int pos = rowptr[r] + atomicAdd(&fill[r], 1);
    colidx[pos] = col[e];
}

__global__ void k_selfloop(const int* __restrict__ rowptr, int* __restrict__ colidx) {
    int i = blockIdx.x * blockDim.x + threadIdx.x;
    if (i < N_NODES) colidx[rowptr[i + 1] - 1] = i;
}

// ---------------------------------------------------------------- weight prep
// Wt[n*K + k] = bf16(W[k*N + n])

__global__ void k_prep_w(const float* __restrict__ W, short* __restrict__ Wt,
                         int K, int N) {
    int idx = blockIdx.x * blockDim.x + threadIdx.x;
    if (idx >= K * N) return;
    int n = idx / K, k = idx - n * K;
    Wt[idx] = f2bf(W[(size_t)k * N + n]);
}

// ---------------------------------------------------------------- MFMA GEMM
// C_bf16[m][n] = dinv[m] * sum_k act(A[m][k]) * W[k][n],  n = 0..255
// A fp32 [M x K]; Wt bf16 [256 x K] (W transposed); act = optional BN+ReLU.
// Block: 256 thr = 4 waves (2x2), tile BM=64 x BN_T=256, BK=64.

#define BM 64
#define BN_T 256
#define BK 64
#define BKP 72   // +8 bf16 pad (16B) -> 2-way bank aliasing only

template <bool BN_ACT>
__global__ __launch_bounds__(256) void k_gemm_mfma(
    const float* __restrict__ A, const short* __restrict__ Wt,
    short* __restrict__ Chs, const float* __restrict__ dinv,
    const float* __restrict__ scale, const float* __restrict__ shift,
    int M, int K) {
    __shared__ __align__(16) short Als[BM * BKP];
    __shared__ __align__(16) short Bls[BN_T * BKP];
    const int t = threadIdx.x;
    const int bm = blockIdx.x * BM;
    const int w = t >> 6, lane = t & 63;
    const int wm = w & 1, wn = w >> 1;
    const int l15 = lane & 15, quad = lane >> 4;

    floatx4 acc[2][8] = {};

    for (int k0 = 0; k0 < K; k0 += BK) {
        // stage A: 64 rows x 64 k, fp32 -> (BN+ReLU) -> bf16
        {
            int r = t >> 2;            // 0..63
            int c = t & 3;             // 16-element k segment
            int gr = bm + r; if (gr >= M) gr = M - 1;
            const float* ap = A + (size_t)gr * K + k0 + c * 16;
            short* lp = Als + r * BKP + c * 16;
#pragma unroll
            for (int i = 0; i < 4; i++) {
                float4 v = *(const float4*)(ap + i * 4);
                if (BN_ACT) {
                    float4 sc = *(const float4*)(scale + k0 + c * 16 + i * 4);
                    float4 sh = *(const float4*)(shift + k0 + c * 16 + i * 4);
                    v.x = fmaxf(fmaf(v.x, sc.x, sh.x), 0.f);
                    v.y = fmaxf(fmaf(v.y, sc.y, sh.y), 0.f);
                    v.z = fmaxf(fmaf(v.z, sc.z, sh.z), 0.f);
                    v.w = fmaxf(fmaf(v.w, sc.w, sh.w), 0.f);
                }
                short4v s;
                s.x = f2bf(v.x); s.y = f2bf(v.y); s.z = f2bf(v.z); s.w = f2bf(v.w);
                *(short4v*)(lp + i * 4) = s;
            }
        }
        // stage B: 256 rows x 64 k bf16 straight copy
        {
            int r0 = t >> 2;           // 0..63
            int c = t & 3;             // 16-element k segment
#pragma unroll
            for (int p = 0; p < 4; p++) {
                int r = r0 + p * 64;
                const short* bp = Wt + (size_t)r * K + k0 + c * 16;
                short* lp = Bls + r * BKP + c * 16;
                *(short8*)(lp) = *(const short8*)(bp);
                *(short8*)(lp + 8) = *(const short8*)(bp + 8);
            }
        }
        __syncthreads();
#pragma unroll
        for (int kc = 0; kc < 2; kc++) {
            short8 af[2], bfr[8];
#pragma unroll
            for (int mi = 0; mi < 2; mi++)
                af[mi] = *(const short8*)(Als + (wm * 32 + mi * 16 + l15) * BKP + kc * 32 + quad * 8);
#pragma unroll
            for (int ni = 0; ni < 8; ni++)
                bfr[ni] = *(const short8*)(Bls + (wn * 128 + ni * 16 + l15) * BKP + kc * 32 + quad * 8);
#pragma unroll
            for (int mi = 0; mi < 2; mi++)
#pragma unroll
                for (int ni = 0; ni < 8; ni++)
                    acc[mi][ni] = __builtin_amdgcn_mfma_f32_16x16x32_bf16(
                        af[mi], bfr[ni], acc[mi][ni], 0, 0, 0);
        }
        __syncthreads();
    }

    // epilogue: scale by dinv[m], store bf16
#pragma unroll
    for (int mi = 0; mi < 2; mi++) {
#pragma unroll
        for (int r = 0; r < 4; r++) {
            int m = bm + wm * 32 + mi * 16 + quad * 4 + r;
            if (m < M) {
                float d = dinv[m];
                size_t base = (size_t)m * BN_T + wn * 128 + l15;
#pragma unroll
                for (int ni = 0; ni < 8; ni++)
                    Chs[base + ni * 16] = f2bf(acc[mi][ni][r] * d);
            }
        }
    }
}

// ---------------------------------------------------------------- fp32 GEMM (final layer)

template <bool BN>
__global__ __launch_bounds__(256) void k_gemm(
    const float* __restrict__ A, const float* __restrict__ W,
    float* __restrict__ C, const float* __restrict__ dinv,
    const float* __restrict__ scale, const float* __restrict__ shift,
    int M, int K, int Nc) {
    const int bm = blockIdx.x * 64;
    const int bn = blockIdx.y * 64;
    __shared__ float As[16][64 + 1];
    __shared__ float Bs[16][64 + 1];
    const int t = threadIdx.x;
    const int tx = t & 15, ty = t >> 4;
    float acc[4][4] = {};
    for (int k0 = 0; k0 < K; k0 += 16) {
#pragma unroll
        for (int i = 0; i < 4; i++) {
            int l = t + i * 256;
            int r = l >> 4, k = l & 15;
            int gm = bm + r, gk = k0 + k;
            float v = 0.f;
            if (gm < M) v = A[(size_t)gm * K + gk];
            if (BN) v = fmaxf(fmaf(v, scale[gk], shift[gk]), 0.f);
            As[k][r] = v;
        }
#pragma unroll
        for (int i = 0; i < 4; i++) {
            int l = t + i * 256;
            int kk = l >> 6, nn = l & 63;
            int gk = k0 + kk, gn = bn + nn;
            float v = 0.f;
            if (gn < Nc) v = W[(size_t)gk * Nc + gn];
            Bs[kk][nn] = v;
        }
        __syncthreads();
#pragma unroll
        for (int kk = 0; kk < 16; kk++) {
            float a[4], b[4];
#pragma unroll
            for (int i = 0; i < 4; i++) a[i] = As[kk][ty * 4 + i];
#pragma unroll
            for (int j = 0; j < 4; j++) b[j] = Bs[kk][tx * 4 + j];
#pragma unroll
            for (int i = 0; i < 4; i++)
#pragma unroll
                for (int j = 0; j < 4; j++)
                    acc[i][j] = fmaf(a[i], b[j], acc[i][j]);
        }
        __syncthreads();
    }
#pragma unroll
    for (int i = 0; i < 4; i++) {
        int gm = bm + ty * 4 + i;
        if (gm >= M) continue;
        float d = dinv[gm];
#pragma unroll
        for (int j = 0; j < 4; j++) {
            int gn = bn + tx * 4 + j;
            if (gn < Nc) C[(size_t)gm * Nc + gn] = acc[i][j] * d;
        }
    }
}

// ---------------------------------------------------------------- aggregation (bf16 in, fp32 out)

__global__ __launch_bounds__(256) void k_aggregate_bf16(
    const short* __restrict__ hs, const int* __restrict__ rowptr,
    const int* __restrict__ colidx, const float* __restrict__ dinv,
    const float* __restrict__ bias, float* __restrict__ out) {
    int gid = blockIdx.x * blockDim.x + threadIdx.x;
    int node = gid >> 6;
    int lane = gid & 63;
    if (node >= N_NODES) return;
    int s = rowptr[node], e = rowptr[node + 1];
    int fo = lane * 4;
    float a0 = 0.f, a1 = 0.f, a2 = 0.f, a3 = 0.f;
    for (int i = s; i < e; i++) {
        int c = colidx[i];
        uint2 u = *(const uint2*)(hs + (size_t)c * DH + fo);
        a0 += bf_lo(u.x); a1 += bf_hi(u.x);
        a2 += bf_lo(u.y); a3 += bf_hi(u.y);
    }
    float d = dinv[node];
    const float4 b = *(const float4*)(bias + fo);
    float4 r;
    r.x = fmaf(a0, d, b.x);
    r.y = fmaf(a1, d, b.y);
    r.z = fmaf(a2, d, b.z);
    r.w = fmaf(a3, d, b.w);
    *(float4*)(out + (size_t)node * DH + fo) = r;
}

// ---------------------------------------------------------------- BN stats

__global__ __launch_bounds__(256) void k_bnstats(const float* __restrict__ o,
                                                 float* __restrict__ psum,
                                                 float* __restrict__ psq) {
    int col = threadIdx.x;
    float s = 0.f, ss = 0.f;
    for (int r = blockIdx.x; r < N_NODES; r += gridDim.x) {
        float v = o[(size_t)r * DH + col];
        s += v;
        ss = fmaf(v, v, ss);
    }
    psum[(size_t)blockIdx.x * DH + col] = s;
    psq[(size_t)blockIdx.x * DH + col] = ss;
}

__global__ __launch_bounds__(256) void k_bnfinal(
    const float* __restrict__ psum, const float* __restrict__ psq,
    const float* __restrict__ gamma, const float* __restrict__ beta,
    float* __restrict__ scale, float* __restrict__ shift) {
    int c = threadIdx.x;
    float s = 0.f, ss = 0.f;
    for (int b = 0; b < STATS_BLOCKS; b++) {
        s += psum[(size_t)b * DH + c];
        ss += psq[(size_t)b * DH + c];
    }
    float mu = s / (float)N_NODES;
    float var = ss / (float)N_NODES - mu * mu;
    float rs = rsqrtf(var + BN_EPS);
    float sc = gamma[c] * rs;
    scale[c] = sc;
    shift[c] = beta[c] - mu * sc;
}

// ---------------------------------------------------------------- final layer

__global__ __launch_bounds__(256) void k_agg_softmax(
    const float* __restrict__ hs, const int* __restrict__ rowptr,
    const int* __restrict__ colidx, const float* __restrict__ dinv,
    const float* __restrict__ bias, float* __restrict__ out) {
    int gid = blockIdx.x * blockDim.x + threadIdx.x;
    int node = gid >> 6;
    int lane = gid & 63;
    if (node >= N_NODES) return;
    int s = rowptr[node], e = rowptr[node + 1];
    float acc = 0.f;
    if (lane < DOUT) {
        for (int i = s; i < e; i++) {
            int c = colidx[i];
            acc += hs[(size_t)c * DOUT + lane];
        }
        acc = fmaf(acc, dinv[node], bias[lane]);
    }
    float v = (lane < DOUT) ? acc : -INFINITY;
    float m = v;
#pragma unroll
    for (int off = 32; off; off >>= 1) m = fmaxf(m, __shfl_xor(m, off));
    float ex = (lane < DOUT) ? expf(acc - m) : 0.f;
    float sum = ex;
#pragma unroll
    for (int off = 32; off; off >>= 1) sum += __shfl_xor(sum, off);
    if (lane < DOUT) out[(size_t)node * DOUT + lane] = acc - m - logf(sum);
}

// ---------------------------------------------------------------- launch

static inline size_t align_up(size_t x, size_t a) { return (x + a - 1) & ~(a - 1); }

extern "C" void kernel_launch(void* const* d_in, const int* in_sizes, int n_in,
                              void* d_out, int out_size, void* d_ws, size_t ws_size,
                              hipStream_t stream) {
    const float* x     = (const float*)d_in[0];   // [N, 128]
    const float* W0    = (const float*)d_in[1];   // [128, 256]
    const float* b0    = (const float*)d_in[2];   // [256]
    const float* Wh    = (const float*)d_in[3];   // [3, 256, 256]
    const float* bh    = (const float*)d_in[4];   // [3, 256]
    const float* gamma = (const float*)d_in[5];   // [4, 256]
    const float* beta  = (const float*)d_in[6];   // [4, 256]
    const float* Wl    = (const float*)d_in[7];   // [256, 40]
    const float* bl    = (const float*)d_in[8];   // [40]
    const int* ei      = (const int*)d_in[9];     // [2, E]
    const int* row = ei;
    const int* col = ei + N_EDGES;
    float* out = (float*)d_out;

    // workspace layout
    char* ws = (char*)d_ws;
    size_t off = 0;
    float* h    = (float*)(ws + off); off = align_up(off + (size_t)N_NODES * DH * 4, 256);   // 102.4MB
    short* hs   = (short*)(ws + off); off = align_up(off + (size_t)N_NODES * DH * 2, 256);   // 51.2MB
    float* hsl  = (float*)(ws + off); off = align_up(off + (size_t)N_NODES * DOUT * 4, 256); // 16MB
    short* wt0  = (short*)(ws + off); off = align_up(off + (size_t)DH * DIN * 2, 256);
    short* wth  = (short*)(ws + off); off = align_up(off + (size_t)3 * DH * DH * 2, 256);
    int* colidx = (int*)(ws + off);  off = align_up(off + (size_t)(N_EDGES + N_NODES) * 4, 256);
    int* cnt    = (int*)(ws + off);  off = align_up(off + (size_t)N_NODES * 4, 256);
    int* fill   = (int*)(ws + off);  off = align_up(off + (size_t)N_NODES * 4, 256);
    int* rowptr = (int*)(ws + off);  off = align_up(off + (size_t)(N_NODES + 1) * 4, 256);
    float* dinv = (float*)(ws + off); off = align_up(off + (size_t)N_NODES * 4, 256);
    float* psum = (float*)(ws + off); off = align_up(off + (size_t)STATS_BLOCKS * DH * 4, 256);
    float* psq  = (float*)(ws + off); off = align_up(off + (size_t)STATS_BLOCKS * DH * 4, 256);
    float* scale = (float*)(ws + off); off = align_up(off + DH * 4, 256);
    float* shift = (float*)(ws + off); off = align_up(off + DH * 4, 256);
    (void)ws_size; (void)n_in; (void)in_sizes; (void)out_size;

    hipMemsetAsync(cnt, 0, (size_t)N_NODES * 4, stream);
    hipMemsetAsync(fill, 0, (size_t)N_NODES * 4, stream);

    const int EB = (N_EDGES + 255) / 256;
    const int NBK = (N_NODES + 255) / 256;
    k_count<<<EB, 256, 0, stream>>>(row, cnt);
    k_dinv<<<NBK, 256, 0, stream>>>(cnt, dinv);
    k_scan<<<1, 1024, 0, stream>>>(cnt, rowptr, N_NODES);
    k_scatter<<<EB, 256, 0, stream>>>(row, col, rowptr, fill, colidx);
    k_selfloop<<<NBK, 256, 0, stream>>>(rowptr, colidx);

    // transpose+convert weights (bf16)
    k_prep_w<<<(DIN * DH + 255) / 256, 256, 0, stream>>>(W0, wt0, DIN, DH);
    for (int i = 0; i < 3; i++)
        k_prep_w<<<(DH * DH + 255) / 256, 256, 0, stream>>>(
            Wh + (size_t)i * DH * DH, wth + (size_t)i * DH * DH, DH, DH);

    const int gemm_blocks = (N_NODES + BM - 1) / BM;
    const int agg_blocks = (N_NODES * 64 + 255) / 256;

    // Layer 0: hs = dinv * (x @ W0), bf16
    k_gemm_mfma<false><<<gemm_blocks, 256, 0, stream>>>(x, wt0, hs, dinv,
                                                        nullptr, nullptr, N_NODES, DIN);
    k_aggregate_bf16<<<agg_blocks, 256, 0, stream>>>(hs, rowptr, colidx, dinv, b0, h);
    k_bnstats<<<STATS_BLOCKS, 256, 0, stream>>>(h, psum, psq);
    k_bnfinal<<<1, 256, 0, stream>>>(psum, psq, gamma, beta, scale, shift);

    // Layers 1..3
    for (int i = 0; i < 3; i++) {
        k_gemm_mfma<true><<<gemm_blocks, 256, 0, stream>>>(
            h, wth + (size_t)i * DH * DH, hs, dinv, scale, shift, N_NODES, DH);
        k_aggregate_bf16<<<agg_blocks, 256, 0, stream>>>(hs, rowptr, colidx, dinv,
                                                         bh + (size_t)i * DH, h);
        k_bnstats<<<STATS_BLOCKS, 256, 0, stream>>>(h, psum, psq);
        k_bnfinal<<<1, 256, 0, stream>>>(psum, psq, gamma + (size_t)(i + 1) * DH,
                                         beta + (size_t)(i + 1) * DH, scale, shift);
    }

    // Layer 4 (fp32): -> DOUT, then fused aggregate + bias + log_softmax
    k_gemm<true><<<dim3((N_NODES + 63) / 64, 1), 256, 0, stream>>>(
        h, Wl, hsl, dinv, scale, shift, N_NODES, DH, DOUT);
    k_agg_softmax<<<agg_blocks, 256, 0, stream>>>(hsl, rowptr, colidx, dinv, bl, out);
}

// Round 3
// 1662.914 us; speedup vs baseline: 1.8126x; 1.1463x over previous
//
#include <hip/hip_runtime.h>
#include <hip/hip_bf16.h>
#include <math.h>
#include <stdint.h>

#define N_NODES 100000
#define N_EDGES 1600000
#define DIN 128
#define DH 256
#define DOUT 40
#define BN_EPS 1e-5f
#define STATS_BLOCKS 512
#define SCAN_BLOCKS ((N_NODES + 1023) / 1024)   // 98

typedef __attribute__((ext_vector_type(8))) short short8;
typedef __attribute__((ext_vector_type(4))) short short4v;
typedef __attribute__((ext_vector_type(4))) float floatx4;

__device__ __forceinline__ short f2bf(float f) {
    uint32_t u = __float_as_uint(f);
    uint32_t r = u + 0x7FFF + ((u >> 16) & 1);   // RNE
    return (short)(r >> 16);
}
__device__ __forceinline__ float bf_lo(uint32_t u) { return __uint_as_float(u << 16); }
__device__ __forceinline__ float bf_hi(uint32_t u) { return __uint_as_float(u & 0xFFFF0000u); }

// ---------------------------------------------------------------- CSR build

__global__ void k_count(const int* __restrict__ row, int* __restrict__ cnt) {
    int e = blockIdx.x * blockDim.x + threadIdx.x;
    if (e < N_EDGES) atomicAdd(&cnt[row[e]], 1);
}

// Pass A: per-block (1024 elems) exclusive scan of cnt[i]+1 -> rowptr (local),
// block totals -> partials. Also computes dinv.
__global__ __launch_bounds__(256) void k_scan_a(const int* __restrict__ cnt,
                                                int* __restrict__ rowptr,
                                                int* __restrict__ partials,
                                                float* __restrict__ dinv, int n) {
    int t = threadIdx.x;
    int idx = blockIdx.x * 1024 + t * 4;
    int a0 = 0, a1 = 0, a2 = 0, a3 = 0;
    if (idx + 3 < n) {
        int4 v = *(const int4*)(cnt + idx);
        a0 = v.x + 1; a1 = v.y + 1; a2 = v.z + 1; a3 = v.w + 1;
    } else {
        if (idx + 0 < n) a0 = cnt[idx + 0] + 1;
        if (idx + 1 < n) a1 = cnt[idx + 1] + 1;
        if (idx + 2 < n) a2 = cnt[idx + 2] + 1;
        if (idx + 3 < n) a3 = cnt[idx + 3] + 1;
    }
    if (idx + 0 < n) dinv[idx + 0] = rsqrtf((float)a0);
    if (idx + 1 < n) dinv[idx + 1] = rsqrtf((float)a1);
    if (idx + 2 < n) dinv[idx + 2] = rsqrtf((float)a2);
    if (idx + 3 < n) dinv[idx + 3] = rsqrtf((float)a3);
    int tsum = a0 + a1 + a2 + a3;
    int lane = t & 63, wid = t >> 6;
    int incl = tsum;
#pragma unroll
    for (int off = 1; off < 64; off <<= 1) {
        int x = __shfl_up(incl, off);
        if (lane >= off) incl += x;
    }
    __shared__ int wsum[4];
    if (lane == 63) wsum[wid] = incl;
    __syncthreads();
    int woff = 0;
    for (int i = 0; i < wid; i++) woff += wsum[i];
    int excl = woff + incl - tsum;
    if (idx + 0 < n) rowptr[idx + 0] = excl;
    if (idx + 1 < n) rowptr[idx + 1] = excl + a0;
    if (idx + 2 < n) rowptr[idx + 2] = excl + a0 + a1;
    if (idx + 3 < n) rowptr[idx + 3] = excl + a0 + a1 + a2;
    if (t == 255) partials[blockIdx.x] = woff + incl;
}

// Pass B: exclusive scan of the 98 partials in-place; write rowptr[n]=total.
__global__ __launch_bounds__(128) void k_scan_b(int* __restrict__ partials,
                                                int* __restrict__ rowptr,
                                                int nb, int n) {
    int t = threadIdx.x;
    int v = (t < nb) ? partials[t] : 0;
    int lane = t & 63, wid = t >> 6;
    int incl = v;
#pragma unroll
    for (int off = 1; off < 64; off <<= 1) {
        int x = __shfl_up(incl, off);
        if (lane >= off) incl += x;
    }
    __shared__ int ws[2];
    if (lane == 63) ws[wid] = incl;
    __syncthreads();
    int woff = (wid == 1) ? ws[0] : 0;
    int excl = woff + incl - v;
    if (t < nb) partials[t] = excl;
    if (t == nb - 1) rowptr[n] = excl + v;
}

// Pass C: add block offsets.
__global__ __launch_bounds__(256) void k_scan_c(int* __restrict__ rowptr,
                                                const int* __restrict__ partials, int n) {
    int off = partials[blockIdx.x];
    if (off == 0) return;
    int idx = blockIdx.x * 1024 + threadIdx.x * 4;
    if (idx + 3 < n) {
        int4 v = *(const int4*)(rowptr + idx);
        v.x += off; v.y += off; v.z += off; v.w += off;
        *(int4*)(rowptr + idx) = v;
    } else {
        for (int i = 0; i < 4; i++)
            if (idx + i < n) rowptr[idx + i] += off;
    }
}

__global__ void k_scatter(const int* __restrict__ row, const int* __restrict__ col,
                          const int* __restrict__ rowptr, int* __restrict__ fill,
                          int* __restrict__ colidx) {
    int e = blockIdx.x * blockDim.x + threadIdx.x;
    if (e >= N_EDGES) return;
    int r = row[e];
    int pos = rowptr[r] + atomicAdd(&fill[r], 1);
    colidx[pos] = col[e];
}

__global__ void k_selfloop(const int* __restrict__ rowptr, int* __restrict__ colidx) {
    int i = blockIdx.x * blockDim.x + threadIdx.x;
    if (i < N_NODES) colidx[rowptr[i + 1] - 1] = i;
}

// ---------------------------------------------------------------- weight prep
// Wt[n*K + k] = bf16(W[k*N + n])

__global__ void k_prep_w(const float* __restrict__ W, short* __restrict__ Wt,
                         int K, int N) {
    int idx = blockIdx.x * blockDim.x + threadIdx.x;
    if (idx >= K * N) return;
    int n = idx / K, k = idx - n * K;
    Wt[idx] = f2bf(W[(size_t)k * N + n]);
}

// Wlt[48 x K]: rows >= DOUT are zero.
__global__ void k_prep_wl(const float* __restrict__ W, short* __restrict__ Wt, int K) {
    int idx = blockIdx.x * blockDim.x + threadIdx.x;
    if (idx >= 48 * K) return;
    int n = idx / K, k = idx - n * K;
    Wt[idx] = (n < DOUT) ? f2bf(W[(size_t)k * DOUT + n]) : (short)0;
}

// ---------------------------------------------------------------- MFMA GEMM
// C_bf16[m][n] = dinv[m] * sum_k act(A[m][k]) * W[k][n],  n = 0..255
// Block: 256 thr = 4 waves (2x2), tile BM=64 x BN_T=256, BK=64.

#define BM 64
#define BN_T 256
#define BK 64
#define BKP 72   // +8 bf16 pad (16B) -> 2-way bank aliasing only

template <bool BN_ACT>
__global__ __launch_bounds__(256) void k_gemm_mfma(
    const float* __restrict__ A, const short* __restrict__ Wt,
    short* __restrict__ Chs, const float* __restrict__ dinv,
    const float* __restrict__ scale, const float* __restrict__ shift,
    int M, int K) {
    __shared__ __align__(16) short Als[BM * BKP];
    __shared__ __align__(16) short Bls[BN_T * BKP];
    const int t = threadIdx.x;
    const int bm = blockIdx.x * BM;
    const int w = t >> 6, lane = t & 63;
    const int wm = w & 1, wn = w >> 1;
    const int l15 = lane & 15, quad = lane >> 4;

    floatx4 acc[2][8] = {};

    for (int k0 = 0; k0 < K; k0 += BK) {
        // stage A: 64 rows x 64 k, fp32 -> (BN+ReLU) -> bf16
        {
            int r = t >> 2;
            int c = t & 3;
            int gr = bm + r; if (gr >= M) gr = M - 1;
            const float* ap = A + (size_t)gr * K + k0 + c * 16;
            short* lp = Als + r * BKP + c * 16;
#pragma unroll
            for (int i = 0; i < 4; i++) {
                float4 v = *(const float4*)(ap + i * 4);
                if (BN_ACT) {
                    float4 sc = *(const float4*)(scale + k0 + c * 16 + i * 4);
                    float4 sh = *(const float4*)(shift + k0 + c * 16 + i * 4);
                    v.x = fmaxf(fmaf(v.x, sc.x, sh.x), 0.f);
                    v.y = fmaxf(fmaf(v.y, sc.y, sh.y), 0.f);
                    v.z = fmaxf(fmaf(v.z, sc.z, sh.z), 0.f);
                    v.w = fmaxf(fmaf(v.w, sc.w, sh.w), 0.f);
                }
                short4v s;
                s.x = f2bf(v.x); s.y = f2bf(v.y); s.z = f2bf(v.z); s.w = f2bf(v.w);
                *(short4v*)(lp + i * 4) = s;
            }
        }
        // stage B: 256 rows x 64 k bf16 straight copy
        {
            int r0 = t >> 2;
            int c = t & 3;
#pragma unroll
            for (int p = 0; p < 4; p++) {
                int r = r0 + p * 64;
                const short* bp = Wt + (size_t)r * K + k0 + c * 16;
                short* lp = Bls + r * BKP + c * 16;
                *(short8*)(lp) = *(const short8*)(bp);
                *(short8*)(lp + 8) = *(const short8*)(bp + 8);
            }
        }
        __syncthreads();
#pragma unroll
        for (int kc = 0; kc < 2; kc++) {
            short8 af[2], bfr[8];
#pragma unroll
            for (int mi = 0; mi < 2; mi++)
                af[mi] = *(const short8*)(Als + (wm * 32 + mi * 16 + l15) * BKP + kc * 32 + quad * 8);
#pragma unroll
            for (int ni = 0; ni < 8; ni++)
                bfr[ni] = *(const short8*)(Bls + (wn * 128 + ni * 16 + l15) * BKP + kc * 32 + quad * 8);
#pragma unroll
            for (int mi = 0; mi < 2; mi++)
#pragma unroll
                for (int ni = 0; ni < 8; ni++)
                    acc[mi][ni] = __builtin_amdgcn_mfma_f32_16x16x32_bf16(
                        af[mi], bfr[ni], acc[mi][ni], 0, 0, 0);
        }
        __syncthreads();
    }

#pragma unroll
    for (int mi = 0; mi < 2; mi++) {
#pragma unroll
        for (int r = 0; r < 4; r++) {
            int m = bm + wm * 32 + mi * 16 + quad * 4 + r;
            if (m < M) {
                float d = dinv[m];
                size_t base = (size_t)m * BN_T + wn * 128 + l15;
#pragma unroll
                for (int ni = 0; ni < 8; ni++)
                    Chs[base + ni * 16] = f2bf(acc[mi][ni][r] * d);
            }
        }
    }
}

// ---------------------------------------------------------------- MFMA GEMM, final layer
// C_f32[m][n] = dinv[m] * sum_k act(A[m][k]) * Wl[k][n], n = 0..39 (padded 48)
// Block: 256 thr = 4 waves, tile BM=64 x 48, each wave 16 rows x 48 cols.

__global__ __launch_bounds__(256) void k_gemm_last(
    const float* __restrict__ A, const short* __restrict__ Wt,
    float* __restrict__ C, const float* __restrict__ dinv,
    const float* __restrict__ scale, const float* __restrict__ shift, int M) {
    __shared__ __align__(16) short Als[BM * BKP];
    __shared__ __align__(16) short Bls[48 * BKP];
    const int t = threadIdx.x;
    const int bm = blockIdx.x * BM;
    const int w = t >> 6, lane = t & 63;
    const int l15 = lane & 15, quad = lane >> 4;
    const int K = DH;

    floatx4 acc[3] = {};

    for (int k0 = 0; k0 < K; k0 += BK) {
        {
            int r = t >> 2;
            int c = t & 3;
            int gr = bm + r; if (gr >= M) gr = M - 1;
            const float* ap = A + (size_t)gr * K + k0 + c * 16;
            short* lp = Als + r * BKP + c * 16;
#pragma unroll
            for (int i = 0; i < 4; i++) {
                float4 v = *(const float4*)(ap + i * 4);
                float4 sc = *(const float4*)(scale + k0 + c * 16 + i * 4);
                float4 sh = *(const float4*)(shift + k0 + c * 16 + i * 4);
                v.x = fmaxf(fmaf(v.x, sc.x, sh.x), 0.f);
                v.y = fmaxf(fmaf(v.y, sc.y, sh.y), 0.f);
                v.z = fmaxf(fmaf(v.z, sc.z, sh.z), 0.f);
                v.w = fmaxf(fmaf(v.w, sc.w, sh.w), 0.f);
                short4v s;
                s.x = f2bf(v.x); s.y = f2bf(v.y); s.z = f2bf(v.z); s.w = f2bf(v.w);
                *(short4v*)(lp + i * 4) = s;
            }
        }
        if (t < 192) {
            int r = t >> 2;    // 0..47
            int c = t & 3;
            const short* bp = Wt + (size_t)r * K + k0 + c * 16;
            short* lp = Bls + r * BKP + c * 16;
            *(short8*)(lp) = *(const short8*)(bp);
            *(short8*)(lp + 8) = *(const short8*)(bp + 8);
        }
        __syncthreads();
#pragma unroll
        for (int kc = 0; kc < 2; kc++) {
            short8 af = *(const short8*)(Als + (w * 16 + l15) * BKP + kc * 32 + quad * 8);
#pragma unroll
            for (int ni = 0; ni < 3; ni++) {
                short8 bfr = *(const short8*)(Bls + (ni * 16 + l15) * BKP + kc * 32 + quad * 8);
                acc[ni] = __builtin_amdgcn_mfma_f32_16x16x32_bf16(af, bfr, acc[ni], 0, 0, 0);
            }
        }
        __syncthreads();
    }

#pragma unroll
    for (int r = 0; r < 4; r++) {
        int m = bm + w * 16 + quad * 4 + r;
        if (m >= M) continue;
        float d = dinv[m];
#pragma unroll
        for (int ni = 0; ni < 3; ni++) {
            int n = ni * 16 + l15;
            if (n < DOUT) C[(size_t)m * DOUT + n] = acc[ni][r] * d;
        }
    }
}

// ---------------------------------------------------------------- aggregation (bf16 in, fp32 out)

__global__ __launch_bounds__(256) void k_aggregate_bf16(
    const short* __restrict__ hs, const int* __restrict__ rowptr,
    const int* __restrict__ colidx, const float* __restrict__ dinv,
    const float* __restrict__ bias, float* __restrict__ out) {
    int gid = blockIdx.x * blockDim.x + threadIdx.x;
    int node = gid >> 6;
    int lane = gid & 63;
    if (node >= N_NODES) return;
    int s = rowptr[node], e = rowptr[node + 1];
    int fo = lane * 4;
    float a0 = 0.f, a1 = 0.f, a2 = 0.f, a3 = 0.f;
    for (int i = s; i < e; i++) {
        int c = colidx[i];
        uint2 u = *(const uint2*)(hs + (size_t)c * DH + fo);
        a0 += bf_lo(u.x); a1 += bf_hi(u.x);
        a2 += bf_lo(u.y); a3 += bf_hi(u.y);
    }
    float d = dinv[node];
    const float4 b = *(const float4*)(bias + fo);
    float4 r;
    r.x = fmaf(a0, d, b.x);
    r.y = fmaf(a1, d, b.y);
    r.z = fmaf(a2, d, b.z);
    r.w = fmaf(a3, d, b.w);
    *(float4*)(out + (size_t)node * DH + fo) = r;
}

// ---------------------------------------------------------------- BN stats

__global__ __launch_bounds__(256) void k_bnstats(const float* __restrict__ o,
                                                 float* __restrict__ psum,
                                                 float* __restrict__ psq) {
    int col = threadIdx.x;
    float s = 0.f, ss = 0.f;
    for (int r = blockIdx.x; r < N_NODES; r += gridDim.x) {
        float v = o[(size_t)r * DH + col];
        s += v;
        ss = fmaf(v, v, ss);
    }
    psum[(size_t)blockIdx.x * DH + col] = s;
    psq[(size_t)blockIdx.x * DH + col] = ss;
}

__global__ __launch_bounds__(256) void k_bnfinal(
    const float* __restrict__ psum, const float* __restrict__ psq,
    const float* __restrict__ gamma, const float* __restrict__ beta,
    float* __restrict__ scale, float* __restrict__ shift) {
    int c = threadIdx.x;
    float s = 0.f, ss = 0.f;
    for (int b = 0; b < STATS_BLOCKS; b++) {
        s += psum[(size_t)b * DH + c];
        ss += psq[(size_t)b * DH + c];
    }
    float mu = s / (float)N_NODES;
    float var = ss / (float)N_NODES - mu * mu;
    float rs = rsqrtf(var + BN_EPS);
    float sc = gamma[c] * rs;
    scale[c] = sc;
    shift[c] = beta[c] - mu * sc;
}

// ---------------------------------------------------------------- final layer

__global__ __launch_bounds__(256) void k_agg_softmax(
    const float* __restrict__ hs, const int* __restrict__ rowptr,
    const int* __restrict__ colidx, const float* __restrict__ dinv,
    const float* __restrict__ bias, float* __restrict__ out) {
    int gid = blockIdx.x * blockDim.x + threadIdx.x;
    int node = gid >> 6;
    int lane = gid & 63;
    if (node >= N_NODES) return;
    int s = rowptr[node], e = rowptr[node + 1];
    float acc = 0.f;
    if (lane < DOUT) {
        for (int i = s; i < e; i++) {
            int c = colidx[i];
            acc += hs[(size_t)c * DOUT + lane];
        }
        acc = fmaf(acc, dinv[node], bias[lane]);
    }
    float v = (lane < DOUT) ? acc : -INFINITY;
    float m = v;
#pragma unroll
    for (int off = 32; off; off >>= 1) m = fmaxf(m, __shfl_xor(m, off));
    float ex = (lane < DOUT) ? expf(acc - m) : 0.f;
    float sum = ex;
#pragma unroll
    for (int off = 32; off; off >>= 1) sum += __shfl_xor(sum, off);
    if (lane < DOUT) out[(size_t)node * DOUT + lane] = acc - m - logf(sum);
}

// ---------------------------------------------------------------- launch

static inline size_t align_up(size_t x, size_t a) { return (x + a - 1) & ~(a - 1); }

extern "C" void kernel_launch(void* const* d_in, const int* in_sizes, int n_in,
                              void* d_out, int out_size, void* d_ws, size_t ws_size,
                              hipStream_t stream) {
    const float* x     = (const float*)d_in[0];   // [N, 128]
    const float* W0    = (const float*)d_in[1];   // [128, 256]
    const float* b0    = (const float*)d_in[2];   // [256]
    const float* Wh    = (const float*)d_in[3];   // [3, 256, 256]
    const float* bh    = (const float*)d_in[4];   // [3, 256]
    const float* gamma = (const float*)d_in[5];   // [4, 256]
    const float* beta  = (const float*)d_in[6];   // [4, 256]
    const float* Wl    = (const float*)d_in[7];   // [256, 40]
    const float* bl    = (const float*)d_in[8];   // [40]
    const int* ei      = (const int*)d_in[9];     // [2, E]
    const int* row = ei;
    const int* col = ei + N_EDGES;
    float* out = (float*)d_out;

    // workspace layout
    char* ws = (char*)d_ws;
    size_t off = 0;
    float* h    = (float*)(ws + off); off = align_up(off + (size_t)N_NODES * DH * 4, 256);   // 102.4MB
    short* hs   = (short*)(ws + off); off = align_up(off + (size_t)N_NODES * DH * 2, 256);   // 51.2MB
    float* hsl  = (float*)(ws + off); off = align_up(off + (size_t)N_NODES * DOUT * 4, 256); // 16MB
    short* wt0  = (short*)(ws + off); off = align_up(off + (size_t)DH * DIN * 2, 256);
    short* wth  = (short*)(ws + off); off = align_up(off + (size_t)3 * DH * DH * 2, 256);
    short* wtl  = (short*)(ws + off); off = align_up(off + (size_t)48 * DH * 2, 256);
    int* colidx = (int*)(ws + off);  off = align_up(off + (size_t)(N_EDGES + N_NODES) * 4, 256);
    int* cnt    = (int*)(ws + off);  off = align_up(off + (size_t)N_NODES * 4, 256);
    int* fill   = (int*)(ws + off);  off = align_up(off + (size_t)N_NODES * 4, 256);
    int* rowptr = (int*)(ws + off);  off = align_up(off + (size_t)(N_NODES + 1) * 4, 256);
    int* partials = (int*)(ws + off); off = align_up(off + (size_t)SCAN_BLOCKS * 4, 256);
    float* dinv = (float*)(ws + off); off = align_up(off + (size_t)N_NODES * 4, 256);
    float* psum = (float*)(ws + off); off = align_up(off + (size_t)STATS_BLOCKS * DH * 4, 256);
    float* psq  = (float*)(ws + off); off = align_up(off + (size_t)STATS_BLOCKS * DH * 4, 256);
    float* scale = (float*)(ws + off); off = align_up(off + DH * 4, 256);
    float* shift = (float*)(ws + off); off = align_up(off + DH * 4, 256);
    (void)ws_size; (void)n_in; (void)in_sizes; (void)out_size;

    hipMemsetAsync(cnt, 0, (size_t)N_NODES * 4, stream);
    hipMemsetAsync(fill, 0, (size_t)N_NODES * 4, stream);

    const int EB = (N_EDGES + 255) / 256;
    const int NBK = (N_NODES + 255) / 256;
    k_count<<<EB, 256, 0, stream>>>(row, cnt);
    k_scan_a<<<SCAN_BLOCKS, 256, 0, stream>>>(cnt, rowptr, partials, dinv, N_NODES);
    k_scan_b<<<1, 128, 0, stream>>>(partials, rowptr, SCAN_BLOCKS, N_NODES);
    k_scan_c<<<SCAN_BLOCKS, 256, 0, stream>>>(rowptr, partials, N_NODES);
    k_scatter<<<EB, 256, 0, stream>>>(row, col, rowptr, fill, colidx);
    k_selfloop<<<NBK, 256, 0, stream>>>(rowptr, colidx);

    // transpose+convert weights (bf16)
    k_prep_w<<<(DIN * DH + 255) / 256, 256, 0, stream>>>(W0, wt0, DIN, DH);
    for (int i = 0; i < 3; i++)
        k_prep_w<<<(DH * DH + 255) / 256, 256, 0, stream>>>(
            Wh + (size_t)i * DH * DH, wth + (size_t)i * DH * DH, DH, DH);
    k_prep_wl<<<(48 * DH + 255) / 256, 256, 0, stream>>>(Wl, wtl, DH);

    const int gemm_blocks = (N_NODES + BM - 1) / BM;
    const int agg_blocks = (N_NODES * 64 + 255) / 256;

    // Layer 0: hs = dinv * (x @ W0), bf16
    k_gemm_mfma<false><<<gemm_blocks, 256, 0, stream>>>(x, wt0, hs, dinv,
                                                        nullptr, nullptr, N_NODES, DIN);
    k_aggregate_bf16<<<agg_blocks, 256, 0, stream>>>(hs, rowptr, colidx, dinv, b0, h);
    k_bnstats<<<STATS_BLOCKS, 256, 0, stream>>>(h, psum, psq);
    k_bnfinal<<<1, 256, 0, stream>>>(psum, psq, gamma, beta, scale, shift);

    // Layers 1..3
    for (int i = 0; i < 3; i++) {
        k_gemm_mfma<true><<<gemm_blocks, 256, 0, stream>>>(
            h, wth + (size_t)i * DH * DH, hs, dinv, scale, shift, N_NODES, DH);
        k_aggregate_bf16<<<agg_blocks, 256, 0, stream>>>(hs, rowptr, colidx, dinv,
                                                         bh + (size_t)i * DH, h);
        k_bnstats<<<STATS_BLOCKS, 256, 0, stream>>>(h, psum, psq);
        k_bnfinal<<<1, 256, 0, stream>>>(psum, psq, gamma + (size_t)(i + 1) * DH,
                                         beta + (size_t)(i + 1) * DH, scale, shift);
    }

    // Layer 4: MFMA -> DOUT, then fused aggregate + bias + log_softmax
    k_gemm_last<<<gemm_blocks, 256, 0, stream>>>(h, wtl, hsl, dinv, scale, shift, N_NODES);
    k_agg_softmax<<<agg_blocks, 256, 0, stream>>>(hsl, rowptr, colidx, dinv, bl, out);
}

// Round 4
// 1348.652 us; speedup vs baseline: 2.2350x; 1.2330x over previous
//
#include <hip/hip_runtime.h>
#include <hip/hip_bf16.h>
#include <math.h>
#include <stdint.h>

#define N_NODES 100000
#define N_EDGES 1600000
#define DIN 128
#define DH 256
#define DOUT 40
#define DOUTP 48
#define BN_EPS 1e-5f
#define STATS_BLOCKS 512
#define SCAN_BLOCKS ((N_NODES + 1023) / 1024)   // 98

typedef __attribute__((ext_vector_type(8))) short short8;
typedef __attribute__((ext_vector_type(4))) short short4v;
typedef __attribute__((ext_vector_type(4))) float floatx4;

__device__ __forceinline__ short f2bf(float f) {
    uint32_t u = __float_as_uint(f);
    uint32_t r = u + 0x7FFF + ((u >> 16) & 1);   // RNE
    return (short)(r >> 16);
}
__device__ __forceinline__ float bf_lo(uint32_t u) { return __uint_as_float(u << 16); }
__device__ __forceinline__ float bf_hi(uint32_t u) { return __uint_as_float(u & 0xFFFF0000u); }
__device__ __forceinline__ float bfval(short s) {
    return __uint_as_float(((uint32_t)(unsigned short)s) << 16);
}

// ---------------------------------------------------------------- CSR build

__global__ void k_count(const int* __restrict__ row, int* __restrict__ cnt) {
    int e = blockIdx.x * blockDim.x + threadIdx.x;
    if (e < N_EDGES) atomicAdd(&cnt[row[e]], 1);
}

__global__ __launch_bounds__(256) void k_scan_a(const int* __restrict__ cnt,
                                                int* __restrict__ rowptr,
                                                int* __restrict__ partials,
                                                float* __restrict__ dinv, int n) {
    int t = threadIdx.x;
    int idx = blockIdx.x * 1024 + t * 4;
    int a0 = 0, a1 = 0, a2 = 0, a3 = 0;
    if (idx + 3 < n) {
        int4 v = *(const int4*)(cnt + idx);
        a0 = v.x + 1; a1 = v.y + 1; a2 = v.z + 1; a3 = v.w + 1;
    } else {
        if (idx + 0 < n) a0 = cnt[idx + 0] + 1;
        if (idx + 1 < n) a1 = cnt[idx + 1] + 1;
        if (idx + 2 < n) a2 = cnt[idx + 2] + 1;
        if (idx + 3 < n) a3 = cnt[idx + 3] + 1;
    }
    if (idx + 0 < n) dinv[idx + 0] = rsqrtf((float)a0);
    if (idx + 1 < n) dinv[idx + 1] = rsqrtf((float)a1);
    if (idx + 2 < n) dinv[idx + 2] = rsqrtf((float)a2);
    if (idx + 3 < n) dinv[idx + 3] = rsqrtf((float)a3);
    int tsum = a0 + a1 + a2 + a3;
    int lane = t & 63, wid = t >> 6;
    int incl = tsum;
#pragma unroll
    for (int off = 1; off < 64; off <<= 1) {
        int x = __shfl_up(incl, off);
        if (lane >= off) incl += x;
    }
    __shared__ int wsum[4];
    if (lane == 63) wsum[wid] = incl;
    __syncthreads();
    int woff = 0;
    for (int i = 0; i < wid; i++) woff += wsum[i];
    int excl = woff + incl - tsum;
    if (idx + 0 < n) rowptr[idx + 0] = excl;
    if (idx + 1 < n) rowptr[idx + 1] = excl + a0;
    if (idx + 2 < n) rowptr[idx + 2] = excl + a0 + a1;
    if (idx + 3 < n) rowptr[idx + 3] = excl + a0 + a1 + a2;
    if (t == 255) partials[blockIdx.x] = woff + incl;
}

__global__ __launch_bounds__(128) void k_scan_b(int* __restrict__ partials,
                                                int* __restrict__ rowptr,
                                                int nb, int n) {
    int t = threadIdx.x;
    int v = (t < nb) ? partials[t] : 0;
    int lane = t & 63, wid = t >> 6;
    int incl = v;
#pragma unroll
    for (int off = 1; off < 64; off <<= 1) {
        int x = __shfl_up(incl, off);
        if (lane >= off) incl += x;
    }
    __shared__ int ws[2];
    if (lane == 63) ws[wid] = incl;
    __syncthreads();
    int woff = (wid == 1) ? ws[0] : 0;
    int excl = woff + incl - v;
    if (t < nb) partials[t] = excl;
    if (t == nb - 1) rowptr[n] = excl + v;
}

__global__ __launch_bounds__(256) void k_scan_c(int* __restrict__ rowptr,
                                                const int* __restrict__ partials, int n) {
    int off = partials[blockIdx.x];
    if (off == 0) return;
    int idx = blockIdx.x * 1024 + threadIdx.x * 4;
    if (idx + 3 < n) {
        int4 v = *(const int4*)(rowptr + idx);
        v.x += off; v.y += off; v.z += off; v.w += off;
        *(int4*)(rowptr + idx) = v;
    } else {
        for (int i = 0; i < 4; i++)
            if (idx + i < n) rowptr[idx + i] += off;
    }
}

__global__ void k_scatter(const int* __restrict__ row, const int* __restrict__ col,
                          const int* __restrict__ rowptr, int* __restrict__ fill,
                          int* __restrict__ colidx) {
    int e = blockIdx.x * blockDim.x + threadIdx.x;
    if (e >= N_EDGES) return;
    int r = row[e];
    int pos = rowptr[r] + atomicAdd(&fill[r], 1);
    colidx[pos] = col[e];
}

__global__ void k_selfloop(const int* __restrict__ rowptr, int* __restrict__ colidx) {
    int i = blockIdx.x * blockDim.x + threadIdx.x;
    if (i < N_NODES) colidx[rowptr[i + 1] - 1] = i;
}

// ---------------------------------------------------------------- weight prep

__global__ void k_prep_w(const float* __restrict__ W, short* __restrict__ Wt,
                         int K, int N) {
    int idx = blockIdx.x * blockDim.x + threadIdx.x;
    if (idx >= K * N) return;
    int n = idx / K, k = idx - n * K;
    Wt[idx] = f2bf(W[(size_t)k * N + n]);
}

__global__ void k_prep_wl(const float* __restrict__ W, short* __restrict__ Wt, int K) {
    int idx = blockIdx.x * blockDim.x + threadIdx.x;
    if (idx >= DOUTP * K) return;
    int n = idx / K, k = idx - n * K;
    Wt[idx] = (n < DOUT) ? f2bf(W[(size_t)k * DOUT + n]) : (short)0;
}

// ---------------------------------------------------------------- MFMA GEMM
// C_bf16[m][n] = dinv[m] * sum_k act(A[m][k]) * W[k][n],  n = 0..255
// Block: 256 thr = 4 waves (2x2), tile BM=64 x BN_T=256, BK=64.
// ABF16: A is bf16 [M][K]; else fp32. BN_ACT: apply scale/shift+ReLU to A.

#define BM 64
#define BN_T 256
#define BK 64
#define BKP 72   // +8 bf16 pad (16B) -> 2-way bank aliasing only

template <bool ABF16, bool BN_ACT>
__global__ __launch_bounds__(256) void k_gemm_mfma(
    const void* __restrict__ Ap, const short* __restrict__ Wt,
    short* __restrict__ Chs, const float* __restrict__ dinv,
    const float* __restrict__ scale, const float* __restrict__ shift,
    int M, int K) {
    __shared__ __align__(16) short Als[BM * BKP];
    __shared__ __align__(16) short Bls[BN_T * BKP];
    const int t = threadIdx.x;
    const int bm = blockIdx.x * BM;
    const int w = t >> 6, lane = t & 63;
    const int wm = w & 1, wn = w >> 1;
    const int l15 = lane & 15, quad = lane >> 4;

    floatx4 acc[2][8] = {};

    for (int k0 = 0; k0 < K; k0 += BK) {
        // stage A: 64 rows x 64 k -> (BN+ReLU) -> bf16 LDS
        {
            int r = t >> 2;
            int c = t & 3;
            int gr = bm + r; if (gr >= M) gr = M - 1;
            short* lp = Als + r * BKP + c * 16;
            if (ABF16) {
                const short* ap = (const short*)Ap + (size_t)gr * K + k0 + c * 16;
                short8 s0 = *(const short8*)(ap);
                short8 s1 = *(const short8*)(ap + 8);
                if (BN_ACT) {
#pragma unroll
                    for (int i = 0; i < 2; i++) {
                        float4 sc = *(const float4*)(scale + k0 + c * 16 + i * 8);
                        float4 sc2 = *(const float4*)(scale + k0 + c * 16 + i * 8 + 4);
                        float4 sh = *(const float4*)(shift + k0 + c * 16 + i * 8);
                        float4 sh2 = *(const float4*)(shift + k0 + c * 16 + i * 8 + 4);
                        short8& s = i ? s1 : s0;
                        short8 o;
                        o[0] = f2bf(fmaxf(fmaf(bfval(s[0]), sc.x, sh.x), 0.f));
                        o[1] = f2bf(fmaxf(fmaf(bfval(s[1]), sc.y, sh.y), 0.f));
                        o[2] = f2bf(fmaxf(fmaf(bfval(s[2]), sc.z, sh.z), 0.f));
                        o[3] = f2bf(fmaxf(fmaf(bfval(s[3]), sc.w, sh.w), 0.f));
                        o[4] = f2bf(fmaxf(fmaf(bfval(s[4]), sc2.x, sh2.x), 0.f));
                        o[5] = f2bf(fmaxf(fmaf(bfval(s[5]), sc2.y, sh2.y), 0.f));
                        o[6] = f2bf(fmaxf(fmaf(bfval(s[6]), sc2.z, sh2.z), 0.f));
                        o[7] = f2bf(fmaxf(fmaf(bfval(s[7]), sc2.w, sh2.w), 0.f));
                        *(short8*)(lp + i * 8) = o;
                    }
                } else {
                    *(short8*)(lp) = s0;
                    *(short8*)(lp + 8) = s1;
                }
            } else {
                const float* ap = (const float*)Ap + (size_t)gr * K + k0 + c * 16;
#pragma unroll
                for (int i = 0; i < 4; i++) {
                    float4 v = *(const float4*)(ap + i * 4);
                    if (BN_ACT) {
                        float4 sc = *(const float4*)(scale + k0 + c * 16 + i * 4);
                        float4 sh = *(const float4*)(shift + k0 + c * 16 + i * 4);
                        v.x = fmaxf(fmaf(v.x, sc.x, sh.x), 0.f);
                        v.y = fmaxf(fmaf(v.y, sc.y, sh.y), 0.f);
                        v.z = fmaxf(fmaf(v.z, sc.z, sh.z), 0.f);
                        v.w = fmaxf(fmaf(v.w, sc.w, sh.w), 0.f);
                    }
                    short4v s;
                    s.x = f2bf(v.x); s.y = f2bf(v.y); s.z = f2bf(v.z); s.w = f2bf(v.w);
                    *(short4v*)(lp + i * 4) = s;
                }
            }
        }
        // stage B: 256 rows x 64 k bf16 straight copy
        {
            int r0 = t >> 2;
            int c = t & 3;
#pragma unroll
            for (int p = 0; p < 4; p++) {
                int r = r0 + p * 64;
                const short* bp = Wt + (size_t)r * K + k0 + c * 16;
                short* lp = Bls + r * BKP + c * 16;
                *(short8*)(lp) = *(const short8*)(bp);
                *(short8*)(lp + 8) = *(const short8*)(bp + 8);
            }
        }
        __syncthreads();
#pragma unroll
        for (int kc = 0; kc < 2; kc++) {
            short8 af[2], bfr[8];
#pragma unroll
            for (int mi = 0; mi < 2; mi++)
                af[mi] = *(const short8*)(Als + (wm * 32 + mi * 16 + l15) * BKP + kc * 32 + quad * 8);
#pragma unroll
            for (int ni = 0; ni < 8; ni++)
                bfr[ni] = *(const short8*)(Bls + (wn * 128 + ni * 16 + l15) * BKP + kc * 32 + quad * 8);
#pragma unroll
            for (int mi = 0; mi < 2; mi++)
#pragma unroll
                for (int ni = 0; ni < 8; ni++)
                    acc[mi][ni] = __builtin_amdgcn_mfma_f32_16x16x32_bf16(
                        af[mi], bfr[ni], acc[mi][ni], 0, 0, 0);
        }
        __syncthreads();
    }

#pragma unroll
    for (int mi = 0; mi < 2; mi++) {
#pragma unroll
        for (int r = 0; r < 4; r++) {
            int m = bm + wm * 32 + mi * 16 + quad * 4 + r;
            if (m < M) {
                float d = dinv[m];
                size_t base = (size_t)m * BN_T + wn * 128 + l15;
#pragma unroll
                for (int ni = 0; ni < 8; ni++)
                    Chs[base + ni * 16] = f2bf(acc[mi][ni][r] * d);
            }
        }
    }
}

// ---------------------------------------------------------------- MFMA GEMM, final layer
// hsl_bf16[m][0..47] = dinv[m] * sum_k act(h[m][k]) * Wl[k][n]

__global__ __launch_bounds__(256) void k_gemm_last(
    const short* __restrict__ A, const short* __restrict__ Wt,
    short* __restrict__ C, const float* __restrict__ dinv,
    const float* __restrict__ scale, const float* __restrict__ shift, int M) {
    __shared__ __align__(16) short Als[BM * BKP];
    __shared__ __align__(16) short Bls[DOUTP * BKP];
    const int t = threadIdx.x;
    const int bm = blockIdx.x * BM;
    const int w = t >> 6, lane = t & 63;
    const int l15 = lane & 15, quad = lane >> 4;
    const int K = DH;

    floatx4 acc[3] = {};

    for (int k0 = 0; k0 < K; k0 += BK) {
        {
            int r = t >> 2;
            int c = t & 3;
            int gr = bm + r; if (gr >= M) gr = M - 1;
            const short* ap = A + (size_t)gr * K + k0 + c * 16;
            short* lp = Als + r * BKP + c * 16;
            short8 s0 = *(const short8*)(ap);
            short8 s1 = *(const short8*)(ap + 8);
#pragma unroll
            for (int i = 0; i < 2; i++) {
                float4 sc = *(const float4*)(scale + k0 + c * 16 + i * 8);
                float4 sc2 = *(const float4*)(scale + k0 + c * 16 + i * 8 + 4);
                float4 sh = *(const float4*)(shift + k0 + c * 16 + i * 8);
                float4 sh2 = *(const float4*)(shift + k0 + c * 16 + i * 8 + 4);
                short8& s = i ? s1 : s0;
                short8 o;
                o[0] = f2bf(fmaxf(fmaf(bfval(s[0]), sc.x, sh.x), 0.f));
                o[1] = f2bf(fmaxf(fmaf(bfval(s[1]), sc.y, sh.y), 0.f));
                o[2] = f2bf(fmaxf(fmaf(bfval(s[2]), sc.z, sh.z), 0.f));
                o[3] = f2bf(fmaxf(fmaf(bfval(s[3]), sc.w, sh.w), 0.f));
                o[4] = f2bf(fmaxf(fmaf(bfval(s[4]), sc2.x, sh2.x), 0.f));
                o[5] = f2bf(fmaxf(fmaf(bfval(s[5]), sc2.y, sh2.y), 0.f));
                o[6] = f2bf(fmaxf(fmaf(bfval(s[6]), sc2.z, sh2.z), 0.f));
                o[7] = f2bf(fmaxf(fmaf(bfval(s[7]), sc2.w, sh2.w), 0.f));
                *(short8*)(lp + i * 8) = o;
            }
        }
        if (t < 192) {
            int r = t >> 2;    // 0..47
            int c = t & 3;
            const short* bp = Wt + (size_t)r * K + k0 + c * 16;
            short* lp = Bls + r * BKP + c * 16;
            *(short8*)(lp) = *(const short8*)(bp);
            *(short8*)(lp + 8) = *(const short8*)(bp + 8);
        }
        __syncthreads();
#pragma unroll
        for (int kc = 0; kc < 2; kc++) {
            short8 af = *(const short8*)(Als + (w * 16 + l15) * BKP + kc * 32 + quad * 8);
#pragma unroll
            for (int ni = 0; ni < 3; ni++) {
                short8 bfr = *(const short8*)(Bls + (ni * 16 + l15) * BKP + kc * 32 + quad * 8);
                acc[ni] = __builtin_amdgcn_mfma_f32_16x16x32_bf16(af, bfr, acc[ni], 0, 0, 0);
            }
        }
        __syncthreads();
    }

#pragma unroll
    for (int r = 0; r < 4; r++) {
        int m = bm + w * 16 + quad * 4 + r;
        if (m >= M) continue;
        float d = dinv[m];
#pragma unroll
        for (int ni = 0; ni < 3; ni++)
            C[(size_t)m * DOUTP + ni * 16 + l15] = f2bf(acc[ni][r] * d);
    }
}

// ---------------------------------------------------------------- aggregation
// bf16 in, bf16 out; one wave per node, x4 unrolled neighbor loop (MLP).

__global__ __launch_bounds__(256) void k_aggregate_bf16(
    const short* __restrict__ hs, const int* __restrict__ rowptr,
    const int* __restrict__ colidx, const float* __restrict__ dinv,
    const float* __restrict__ bias, short* __restrict__ out) {
    int gid = blockIdx.x * blockDim.x + threadIdx.x;
    int node = gid >> 6;
    int lane = gid & 63;
    if (node >= N_NODES) return;
    int s = rowptr[node], e = rowptr[node + 1];
    const short* base = hs + lane * 4;
    float a0 = 0.f, a1 = 0.f, a2 = 0.f, a3 = 0.f;
    float b0 = 0.f, b1 = 0.f, b2 = 0.f, b3 = 0.f;
    float c0 = 0.f, c1 = 0.f, c2 = 0.f, c3 = 0.f;
    float d0 = 0.f, d1 = 0.f, d2 = 0.f, d3 = 0.f;
    int i = s;
    for (; i + 4 <= e; i += 4) {
        int n0 = colidx[i], n1 = colidx[i + 1], n2 = colidx[i + 2], n3 = colidx[i + 3];
        uint2 u0 = *(const uint2*)(base + (size_t)n0 * DH);
        uint2 u1 = *(const uint2*)(base + (size_t)n1 * DH);
        uint2 u2 = *(const uint2*)(base + (size_t)n2 * DH);
        uint2 u3 = *(const uint2*)(base + (size_t)n3 * DH);
        a0 += bf_lo(u0.x); a1 += bf_hi(u0.x); a2 += bf_lo(u0.y); a3 += bf_hi(u0.y);
        b0 += bf_lo(u1.x); b1 += bf_hi(u1.x); b2 += bf_lo(u1.y); b3 += bf_hi(u1.y);
        c0 += bf_lo(u2.x); c1 += bf_hi(u2.x); c2 += bf_lo(u2.y); c3 += bf_hi(u2.y);
        d0 += bf_lo(u3.x); d1 += bf_hi(u3.x); d2 += bf_lo(u3.y); d3 += bf_hi(u3.y);
    }
    for (; i < e; i++) {
        int n0 = colidx[i];
        uint2 u = *(const uint2*)(base + (size_t)n0 * DH);
        a0 += bf_lo(u.x); a1 += bf_hi(u.x); a2 += bf_lo(u.y); a3 += bf_hi(u.y);
    }
    a0 = (a0 + b0) + (c0 + d0);
    a1 = (a1 + b1) + (c1 + d1);
    a2 = (a2 + b2) + (c2 + d2);
    a3 = (a3 + b3) + (c3 + d3);
    float d = dinv[node];
    const float4 bi = *(const float4*)(bias + lane * 4);
    short4v r;
    r.x = f2bf(fmaf(a0, d, bi.x));
    r.y = f2bf(fmaf(a1, d, bi.y));
    r.z = f2bf(fmaf(a2, d, bi.z));
    r.w = f2bf(fmaf(a3, d, bi.w));
    *(short4v*)(out + (size_t)node * DH + lane * 4) = r;
}

// ---------------------------------------------------------------- BN stats (bf16 input)

__global__ __launch_bounds__(256) void k_bnstats(const short* __restrict__ o,
                                                 float* __restrict__ psum,
                                                 float* __restrict__ psq) {
    int col = threadIdx.x;
    float s = 0.f, ss = 0.f;
    for (int r = blockIdx.x; r < N_NODES; r += gridDim.x) {
        float v = bfval(o[(size_t)r * DH + col]);
        s += v;
        ss = fmaf(v, v, ss);
    }
    psum[(size_t)blockIdx.x * DH + col] = s;
    psq[(size_t)blockIdx.x * DH + col] = ss;
}

__global__ __launch_bounds__(256) void k_bnfinal(
    const float* __restrict__ psum, const float* __restrict__ psq,
    const float* __restrict__ gamma, const float* __restrict__ beta,
    float* __restrict__ scale, float* __restrict__ shift) {
    int c = threadIdx.x;
    float s = 0.f, ss = 0.f;
    for (int b = 0; b < STATS_BLOCKS; b++) {
        s += psum[(size_t)b * DH + c];
        ss += psq[(size_t)b * DH + c];
    }
    float mu = s / (float)N_NODES;
    float var = ss / (float)N_NODES - mu * mu;
    float rs = rsqrtf(var + BN_EPS);
    float sc = gamma[c] * rs;
    scale[c] = sc;
    shift[c] = beta[c] - mu * sc;
}

// ---------------------------------------------------------------- final agg + log_softmax
// hsl bf16 padded to 48 cols; cols 40..47 are zero.

__global__ __launch_bounds__(256) void k_agg_softmax(
    const short* __restrict__ hsl, const int* __restrict__ rowptr,
    const int* __restrict__ colidx, const float* __restrict__ dinv,
    const float* __restrict__ bias, float* __restrict__ out) {
    int gid = blockIdx.x * blockDim.x + threadIdx.x;
    int node = gid >> 6;
    int lane = gid & 63;
    if (node >= N_NODES) return;
    int s = rowptr[node], e = rowptr[node + 1];
    float a = 0.f, b = 0.f, c = 0.f, d = 0.f;
    if (lane < DOUTP) {
        const short* base = hsl + lane;
        int i = s;
        for (; i + 4 <= e; i += 4) {
            int n0 = colidx[i], n1 = colidx[i + 1], n2 = colidx[i + 2], n3 = colidx[i + 3];
            a += bfval(base[(size_t)n0 * DOUTP]);
            b += bfval(base[(size_t)n1 * DOUTP]);
            c += bfval(base[(size_t)n2 * DOUTP]);
            d += bfval(base[(size_t)n3 * DOUTP]);
        }
        for (; i < e; i++) a += bfval(base[(size_t)colidx[i] * DOUTP]);
        a = (a + b) + (c + d);
    }
    float acc = 0.f;
    if (lane < DOUT) acc = fmaf(a, dinv[node], bias[lane]);
    float v = (lane < DOUT) ? acc : -INFINITY;
    float m = v;
#pragma unroll
    for (int off = 32; off; off >>= 1) m = fmaxf(m, __shfl_xor(m, off));
    float ex = (lane < DOUT) ? expf(acc - m) : 0.f;
    float sum = ex;
#pragma unroll
    for (int off = 32; off; off >>= 1) sum += __shfl_xor(sum, off);
    if (lane < DOUT) out[(size_t)node * DOUT + lane] = acc - m - logf(sum);
}

// ---------------------------------------------------------------- launch

static inline size_t align_up(size_t x, size_t a) { return (x + a - 1) & ~(a - 1); }

extern "C" void kernel_launch(void* const* d_in, const int* in_sizes, int n_in,
                              void* d_out, int out_size, void* d_ws, size_t ws_size,
                              hipStream_t stream) {
    const float* x     = (const float*)d_in[0];   // [N, 128]
    const float* W0    = (const float*)d_in[1];   // [128, 256]
    const float* b0    = (const float*)d_in[2];   // [256]
    const float* Wh    = (const float*)d_in[3];   // [3, 256, 256]
    const float* bh    = (const float*)d_in[4];   // [3, 256]
    const float* gamma = (const float*)d_in[5];   // [4, 256]
    const float* beta  = (const float*)d_in[6];   // [4, 256]
    const float* Wl    = (const float*)d_in[7];   // [256, 40]
    const float* bl    = (const float*)d_in[8];   // [40]
    const int* ei      = (const int*)d_in[9];     // [2, E]
    const int* row = ei;
    const int* col = ei + N_EDGES;
    float* out = (float*)d_out;

    // workspace layout
    char* ws = (char*)d_ws;
    size_t off = 0;
    short* h    = (short*)(ws + off); off = align_up(off + (size_t)N_NODES * DH * 2, 256);   // 51.2MB
    short* hs   = (short*)(ws + off); off = align_up(off + (size_t)N_NODES * DH * 2, 256);   // 51.2MB
    short* hsl  = (short*)(ws + off); off = align_up(off + (size_t)N_NODES * DOUTP * 2, 256);// 9.6MB
    short* wt0  = (short*)(ws + off); off = align_up(off + (size_t)DH * DIN * 2, 256);
    short* wth  = (short*)(ws + off); off = align_up(off + (size_t)3 * DH * DH * 2, 256);
    short* wtl  = (short*)(ws + off); off = align_up(off + (size_t)DOUTP * DH * 2, 256);
    int* colidx = (int*)(ws + off);  off = align_up(off + (size_t)(N_EDGES + N_NODES) * 4, 256);
    int* cnt    = (int*)(ws + off);  off = align_up(off + (size_t)N_NODES * 4, 256);
    int* fill   = (int*)(ws + off);  off = align_up(off + (size_t)N_NODES * 4, 256);
    int* rowptr = (int*)(ws + off);  off = align_up(off + (size_t)(N_NODES + 1) * 4, 256);
    int* partials = (int*)(ws + off); off = align_up(off + (size_t)SCAN_BLOCKS * 4, 256);
    float* dinv = (float*)(ws + off); off = align_up(off + (size_t)N_NODES * 4, 256);
    float* psum = (float*)(ws + off); off = align_up(off + (size_t)STATS_BLOCKS * DH * 4, 256);
    float* psq  = (float*)(ws + off); off = align_up(off + (size_t)STATS_BLOCKS * DH * 4, 256);
    float* scale = (float*)(ws + off); off = align_up(off + DH * 4, 256);
    float* shift = (float*)(ws + off); off = align_up(off + DH * 4, 256);
    (void)ws_size; (void)n_in; (void)in_sizes; (void)out_size;

    hipMemsetAsync(cnt, 0, (size_t)N_NODES * 4, stream);
    hipMemsetAsync(fill, 0, (size_t)N_NODES * 4, stream);

    const int EB = (N_EDGES + 255) / 256;
    const int NBK = (N_NODES + 255) / 256;
    k_count<<<EB, 256, 0, stream>>>(row, cnt);
    k_scan_a<<<SCAN_BLOCKS, 256, 0, stream>>>(cnt, rowptr, partials, dinv, N_NODES);
    k_scan_b<<<1, 128, 0, stream>>>(partials, rowptr, SCAN_BLOCKS, N_NODES);
    k_scan_c<<<SCAN_BLOCKS, 256, 0, stream>>>(rowptr, partials, N_NODES);
    k_scatter<<<EB, 256, 0, stream>>>(row, col, rowptr, fill, colidx);
    k_selfloop<<<NBK, 256, 0, stream>>>(rowptr, colidx);

    k_prep_w<<<(DIN * DH + 255) / 256, 256, 0, stream>>>(W0, wt0, DIN, DH);
    for (int i = 0; i < 3; i++)
        k_prep_w<<<(DH * DH + 255) / 256, 256, 0, stream>>>(
            Wh + (size_t)i * DH * DH, wth + (size_t)i * DH * DH, DH, DH);
    k_prep_wl<<<(DOUTP * DH + 255) / 256, 256, 0, stream>>>(Wl, wtl, DH);

    const int gemm_blocks = (N_NODES + BM - 1) / BM;
    const int agg_blocks = (N_NODES * 64 + 255) / 256;

    // Layer 0: hs = dinv * (x @ W0), bf16
    k_gemm_mfma<false, false><<<gemm_blocks, 256, 0, stream>>>(
        x, wt0, hs, dinv, nullptr, nullptr, N_NODES, DIN);
    k_aggregate_bf16<<<agg_blocks, 256, 0, stream>>>(hs, rowptr, colidx, dinv, b0, h);
    k_bnstats<<<STATS_BLOCKS, 256, 0, stream>>>(h, psum, psq);
    k_bnfinal<<<1, 256, 0, stream>>>(psum, psq, gamma, beta, scale, shift);

    // Layers 1..3
    for (int i = 0; i < 3; i++) {
        k_gemm_mfma<true, true><<<gemm_blocks, 256, 0, stream>>>(
            h, wth + (size_t)i * DH * DH, hs, dinv, scale, shift, N_NODES, DH);
        k_aggregate_bf16<<<agg_blocks, 256, 0, stream>>>(hs, rowptr, colidx, dinv,
                                                         bh + (size_t)i * DH, h);
        k_bnstats<<<STATS_BLOCKS, 256, 0, stream>>>(h, psum, psq);
        k_bnfinal<<<1, 256, 0, stream>>>(psum, psq, gamma + (size_t)(i + 1) * DH,
                                         beta + (size_t)(i + 1) * DH, scale, shift);
    }

    // Layer 4: MFMA -> DOUTP bf16, then fused aggregate + bias + log_softmax
    k_gemm_last<<<gemm_blocks, 256, 0, stream>>>(h, wtl, hsl, dinv, scale, shift, N_NODES);
    k_agg_softmax<<<agg_blocks, 256, 0, stream>>>(hsl, rowptr, colidx, dinv, bl, out);
}

// Round 5
// 1324.970 us; speedup vs baseline: 2.2750x; 1.0179x over previous
//
#include <hip/hip_runtime.h>
#include <hip/hip_bf16.h>
#include <math.h>
#include <stdint.h>

#define N_NODES 100000
#define N_EDGES 1600000
#define DIN 128
#define DH 256
#define DOUT 40
#define DOUTP 48
#define BN_EPS 1e-5f
#define STATS_BLOCKS 512
#define SCAN_BLOCKS ((N_NODES + 1023) / 1024)   // 98

typedef __attribute__((ext_vector_type(8))) short short8;
typedef __attribute__((ext_vector_type(4))) short short4v;
typedef __attribute__((ext_vector_type(4))) float floatx4;

__device__ __forceinline__ short f2bf(float f) {
    uint32_t u = __float_as_uint(f);
    uint32_t r = u + 0x7FFF + ((u >> 16) & 1);   // RNE
    return (short)(r >> 16);
}
__device__ __forceinline__ float bf_lo(uint32_t u) { return __uint_as_float(u << 16); }
__device__ __forceinline__ float bf_hi(uint32_t u) { return __uint_as_float(u & 0xFFFF0000u); }
__device__ __forceinline__ float bfval(short s) {
    return __uint_as_float(((uint32_t)(unsigned short)s) << 16);
}

// ---------------------------------------------------------------- CSR build

__global__ void k_count(const int* __restrict__ row, int* __restrict__ cnt) {
    int e = blockIdx.x * blockDim.x + threadIdx.x;
    if (e < N_EDGES) atomicAdd(&cnt[row[e]], 1);
}

__global__ __launch_bounds__(256) void k_scan_a(const int* __restrict__ cnt,
                                                int* __restrict__ rowptr,
                                                int* __restrict__ partials,
                                                float* __restrict__ dinv, int n) {
    int t = threadIdx.x;
    int idx = blockIdx.x * 1024 + t * 4;
    int a0 = 0, a1 = 0, a2 = 0, a3 = 0;
    if (idx + 3 < n) {
        int4 v = *(const int4*)(cnt + idx);
        a0 = v.x + 1; a1 = v.y + 1; a2 = v.z + 1; a3 = v.w + 1;
    } else {
        if (idx + 0 < n) a0 = cnt[idx + 0] + 1;
        if (idx + 1 < n) a1 = cnt[idx + 1] + 1;
        if (idx + 2 < n) a2 = cnt[idx + 2] + 1;
        if (idx + 3 < n) a3 = cnt[idx + 3] + 1;
    }
    if (idx + 0 < n) dinv[idx + 0] = rsqrtf((float)a0);
    if (idx + 1 < n) dinv[idx + 1] = rsqrtf((float)a1);
    if (idx + 2 < n) dinv[idx + 2] = rsqrtf((float)a2);
    if (idx + 3 < n) dinv[idx + 3] = rsqrtf((float)a3);
    int tsum = a0 + a1 + a2 + a3;
    int lane = t & 63, wid = t >> 6;
    int incl = tsum;
#pragma unroll
    for (int off = 1; off < 64; off <<= 1) {
        int x = __shfl_up(incl, off);
        if (lane >= off) incl += x;
    }
    __shared__ int wsum[4];
    if (lane == 63) wsum[wid] = incl;
    __syncthreads();
    int woff = 0;
    for (int i = 0; i < wid; i++) woff += wsum[i];
    int excl = woff + incl - tsum;
    if (idx + 0 < n) rowptr[idx + 0] = excl;
    if (idx + 1 < n) rowptr[idx + 1] = excl + a0;
    if (idx + 2 < n) rowptr[idx + 2] = excl + a0 + a1;
    if (idx + 3 < n) rowptr[idx + 3] = excl + a0 + a1 + a2;
    if (t == 255) partials[blockIdx.x] = woff + incl;
}

__global__ __launch_bounds__(128) void k_scan_b(int* __restrict__ partials,
                                                int* __restrict__ rowptr,
                                                int nb, int n) {
    int t = threadIdx.x;
    int v = (t < nb) ? partials[t] : 0;
    int lane = t & 63, wid = t >> 6;
    int incl = v;
#pragma unroll
    for (int off = 1; off < 64; off <<= 1) {
        int x = __shfl_up(incl, off);
        if (lane >= off) incl += x;
    }
    __shared__ int ws[2];
    if (lane == 63) ws[wid] = incl;
    __syncthreads();
    int woff = (wid == 1) ? ws[0] : 0;
    int excl = woff + incl - v;
    if (t < nb) partials[t] = excl;
    if (t == nb - 1) rowptr[n] = excl + v;
}

__global__ __launch_bounds__(256) void k_scan_c(int* __restrict__ rowptr,
                                                const int* __restrict__ partials, int n) {
    int off = partials[blockIdx.x];
    if (off == 0) return;
    int idx = blockIdx.x * 1024 + threadIdx.x * 4;
    if (idx + 3 < n) {
        int4 v = *(const int4*)(rowptr + idx);
        v.x += off; v.y += off; v.z += off; v.w += off;
        *(int4*)(rowptr + idx) = v;
    } else {
        for (int i = 0; i < 4; i++)
            if (idx + i < n) rowptr[idx + i] += off;
    }
}

__global__ void k_scatter(const int* __restrict__ row, const int* __restrict__ col,
                          const int* __restrict__ rowptr, int* __restrict__ fill,
                          int* __restrict__ colidx) {
    int e = blockIdx.x * blockDim.x + threadIdx.x;
    if (e >= N_EDGES) return;
    int r = row[e];
    int pos = rowptr[r] + atomicAdd(&fill[r], 1);
    colidx[pos] = col[e];
}

__global__ void k_selfloop(const int* __restrict__ rowptr, int* __restrict__ colidx) {
    int i = blockIdx.x * blockDim.x + threadIdx.x;
    if (i < N_NODES) colidx[rowptr[i + 1] - 1] = i;
}

// ---------------------------------------------------------------- weight prep

__global__ void k_prep_w(const float* __restrict__ W, short* __restrict__ Wt,
                         int K, int N) {
    int idx = blockIdx.x * blockDim.x + threadIdx.x;
    if (idx >= K * N) return;
    int n = idx / K, k = idx - n * K;
    Wt[idx] = f2bf(W[(size_t)k * N + n]);
}

__global__ void k_prep_wl(const float* __restrict__ W, short* __restrict__ Wt, int K) {
    int idx = blockIdx.x * blockDim.x + threadIdx.x;
    if (idx >= DOUTP * K) return;
    int n = idx / K, k = idx - n * K;
    Wt[idx] = (n < DOUT) ? f2bf(W[(size_t)k * DOUT + n]) : (short)0;
}

// ---------------------------------------------------------------- MFMA GEMM
// C_bf16[m][n] = dinv[m] * sum_k act(A[m][k]) * W[k][n],  n = 0..255
// Block: 256 thr = 4 waves (2x2), tile BM=64 x BN_T=256, BK=64.

#define BM 64
#define BN_T 256
#define BK 64
#define BKP 72   // +8 bf16 pad (16B) -> 2-way bank aliasing only

template <bool ABF16, bool BN_ACT>
__global__ __launch_bounds__(256) void k_gemm_mfma(
    const void* __restrict__ Ap, const short* __restrict__ Wt,
    short* __restrict__ Chs, const float* __restrict__ dinv,
    const float* __restrict__ scale, const float* __restrict__ shift,
    int M, int K) {
    __shared__ __align__(16) short Als[BM * BKP];
    __shared__ __align__(16) short Bls[BN_T * BKP];
    const int t = threadIdx.x;
    const int bm = blockIdx.x * BM;
    const int w = t >> 6, lane = t & 63;
    const int wm = w & 1, wn = w >> 1;
    const int l15 = lane & 15, quad = lane >> 4;

    floatx4 acc[2][8] = {};

    for (int k0 = 0; k0 < K; k0 += BK) {
        {
            int r = t >> 2;
            int c = t & 3;
            int gr = bm + r; if (gr >= M) gr = M - 1;
            short* lp = Als + r * BKP + c * 16;
            if (ABF16) {
                const short* ap = (const short*)Ap + (size_t)gr * K + k0 + c * 16;
                short8 s0 = *(const short8*)(ap);
                short8 s1 = *(const short8*)(ap + 8);
                if (BN_ACT) {
#pragma unroll
                    for (int i = 0; i < 2; i++) {
                        float4 sc = *(const float4*)(scale + k0 + c * 16 + i * 8);
                        float4 sc2 = *(const float4*)(scale + k0 + c * 16 + i * 8 + 4);
                        float4 sh = *(const float4*)(shift + k0 + c * 16 + i * 8);
                        float4 sh2 = *(const float4*)(shift + k0 + c * 16 + i * 8 + 4);
                        short8& s = i ? s1 : s0;
                        short8 o;
                        o[0] = f2bf(fmaxf(fmaf(bfval(s[0]), sc.x, sh.x), 0.f));
                        o[1] = f2bf(fmaxf(fmaf(bfval(s[1]), sc.y, sh.y), 0.f));
                        o[2] = f2bf(fmaxf(fmaf(bfval(s[2]), sc.z, sh.z), 0.f));
                        o[3] = f2bf(fmaxf(fmaf(bfval(s[3]), sc.w, sh.w), 0.f));
                        o[4] = f2bf(fmaxf(fmaf(bfval(s[4]), sc2.x, sh2.x), 0.f));
                        o[5] = f2bf(fmaxf(fmaf(bfval(s[5]), sc2.y, sh2.y), 0.f));
                        o[6] = f2bf(fmaxf(fmaf(bfval(s[6]), sc2.z, sh2.z), 0.f));
                        o[7] = f2bf(fmaxf(fmaf(bfval(s[7]), sc2.w, sh2.w), 0.f));
                        *(short8*)(lp + i * 8) = o;
                    }
                } else {
                    *(short8*)(lp) = s0;
                    *(short8*)(lp + 8) = s1;
                }
            } else {
                const float* ap = (const float*)Ap + (size_t)gr * K + k0 + c * 16;
#pragma unroll
                for (int i = 0; i < 4; i++) {
                    float4 v = *(const float4*)(ap + i * 4);
                    if (BN_ACT) {
                        float4 sc = *(const float4*)(scale + k0 + c * 16 + i * 4);
                        float4 sh = *(const float4*)(shift + k0 + c * 16 + i * 4);
                        v.x = fmaxf(fmaf(v.x, sc.x, sh.x), 0.f);
                        v.y = fmaxf(fmaf(v.y, sc.y, sh.y), 0.f);
                        v.z = fmaxf(fmaf(v.z, sc.z, sh.z), 0.f);
                        v.w = fmaxf(fmaf(v.w, sc.w, sh.w), 0.f);
                    }
                    short4v s;
                    s.x = f2bf(v.x); s.y = f2bf(v.y); s.z = f2bf(v.z); s.w = f2bf(v.w);
                    *(short4v*)(lp + i * 4) = s;
                }
            }
        }
        {
            int r0 = t >> 2;
            int c = t & 3;
#pragma unroll
            for (int p = 0; p < 4; p++) {
                int r = r0 + p * 64;
                const short* bp = Wt + (size_t)r * K + k0 + c * 16;
                short* lp = Bls + r * BKP + c * 16;
                *(short8*)(lp) = *(const short8*)(bp);
                *(short8*)(lp + 8) = *(const short8*)(bp + 8);
            }
        }
        __syncthreads();
#pragma unroll
        for (int kc = 0; kc < 2; kc++) {
            short8 af[2], bfr[8];
#pragma unroll
            for (int mi = 0; mi < 2; mi++)
                af[mi] = *(const short8*)(Als + (wm * 32 + mi * 16 + l15) * BKP + kc * 32 + quad * 8);
#pragma unroll
            for (int ni = 0; ni < 8; ni++)
                bfr[ni] = *(const short8*)(Bls + (wn * 128 + ni * 16 + l15) * BKP + kc * 32 + quad * 8);
#pragma unroll
            for (int mi = 0; mi < 2; mi++)
#pragma unroll
                for (int ni = 0; ni < 8; ni++)
                    acc[mi][ni] = __builtin_amdgcn_mfma_f32_16x16x32_bf16(
                        af[mi], bfr[ni], acc[mi][ni], 0, 0, 0);
        }
        __syncthreads();
    }

#pragma unroll
    for (int mi = 0; mi < 2; mi++) {
#pragma unroll
        for (int r = 0; r < 4; r++) {
            int m = bm + wm * 32 + mi * 16 + quad * 4 + r;
            if (m < M) {
                float d = dinv[m];
                size_t base = (size_t)m * BN_T + wn * 128 + l15;
#pragma unroll
                for (int ni = 0; ni < 8; ni++)
                    Chs[base + ni * 16] = f2bf(acc[mi][ni][r] * d);
            }
        }
    }
}

// ---------------------------------------------------------------- MFMA GEMM, final layer

__global__ __launch_bounds__(256) void k_gemm_last(
    const short* __restrict__ A, const short* __restrict__ Wt,
    short* __restrict__ C, const float* __restrict__ dinv,
    const float* __restrict__ scale, const float* __restrict__ shift, int M) {
    __shared__ __align__(16) short Als[BM * BKP];
    __shared__ __align__(16) short Bls[DOUTP * BKP];
    const int t = threadIdx.x;
    const int bm = blockIdx.x * BM;
    const int w = t >> 6, lane = t & 63;
    const int l15 = lane & 15, quad = lane >> 4;
    const int K = DH;

    floatx4 acc[3] = {};

    for (int k0 = 0; k0 < K; k0 += BK) {
        {
            int r = t >> 2;
            int c = t & 3;
            int gr = bm + r; if (gr >= M) gr = M - 1;
            const short* ap = A + (size_t)gr * K + k0 + c * 16;
            short* lp = Als + r * BKP + c * 16;
            short8 s0 = *(const short8*)(ap);
            short8 s1 = *(const short8*)(ap + 8);
#pragma unroll
            for (int i = 0; i < 2; i++) {
                float4 sc = *(const float4*)(scale + k0 + c * 16 + i * 8);
                float4 sc2 = *(const float4*)(scale + k0 + c * 16 + i * 8 + 4);
                float4 sh = *(const float4*)(shift + k0 + c * 16 + i * 8);
                float4 sh2 = *(const float4*)(shift + k0 + c * 16 + i * 8 + 4);
                short8& s = i ? s1 : s0;
                short8 o;
                o[0] = f2bf(fmaxf(fmaf(bfval(s[0]), sc.x, sh.x), 0.f));
                o[1] = f2bf(fmaxf(fmaf(bfval(s[1]), sc.y, sh.y), 0.f));
                o[2] = f2bf(fmaxf(fmaf(bfval(s[2]), sc.z, sh.z), 0.f));
                o[3] = f2bf(fmaxf(fmaf(bfval(s[3]), sc.w, sh.w), 0.f));
                o[4] = f2bf(fmaxf(fmaf(bfval(s[4]), sc2.x, sh2.x), 0.f));
                o[5] = f2bf(fmaxf(fmaf(bfval(s[5]), sc2.y, sh2.y), 0.f));
                o[6] = f2bf(fmaxf(fmaf(bfval(s[6]), sc2.z, sh2.z), 0.f));
                o[7] = f2bf(fmaxf(fmaf(bfval(s[7]), sc2.w, sh2.w), 0.f));
                *(short8*)(lp + i * 8) = o;
            }
        }
        if (t < 192) {
            int r = t >> 2;    // 0..47
            int c = t & 3;
            const short* bp = Wt + (size_t)r * K + k0 + c * 16;
            short* lp = Bls + r * BKP + c * 16;
            *(short8*)(lp) = *(const short8*)(bp);
            *(short8*)(lp + 8) = *(const short8*)(bp + 8);
        }
        __syncthreads();
#pragma unroll
        for (int kc = 0; kc < 2; kc++) {
            short8 af = *(const short8*)(Als + (w * 16 + l15) * BKP + kc * 32 + quad * 8);
#pragma unroll
            for (int ni = 0; ni < 3; ni++) {
                short8 bfr = *(const short8*)(Bls + (ni * 16 + l15) * BKP + kc * 32 + quad * 8);
                acc[ni] = __builtin_amdgcn_mfma_f32_16x16x32_bf16(af, bfr, acc[ni], 0, 0, 0);
            }
        }
        __syncthreads();
    }

#pragma unroll
    for (int r = 0; r < 4; r++) {
        int m = bm + w * 16 + quad * 4 + r;
        if (m >= M) continue;
        float d = dinv[m];
#pragma unroll
        for (int ni = 0; ni < 3; ni++)
            C[(size_t)m * DOUTP + ni * 16 + l15] = f2bf(acc[ni][r] * d);
    }
}

// ---------------------------------------------------------------- aggregation
// bf16 in/out. One wave per node; half-wave (32 lanes x uint4=16B) covers a
// full 512B row, so one load instr fetches 2 rows (1KB). x4 unroll -> 8
// neighbors in flight. No bias: conv bias cancels exactly in training BN.

__global__ __launch_bounds__(256) void k_aggregate_bf16(
    const short* __restrict__ hs, const int* __restrict__ rowptr,
    const int* __restrict__ colidx, const float* __restrict__ dinv,
    short* __restrict__ out) {
    int gid = blockIdx.x * blockDim.x + threadIdx.x;
    int node = gid >> 6;
    if (node >= N_NODES) return;
    int lane = threadIdx.x & 63;
    int half = lane >> 5;     // 0: even neighbors, 1: odd
    int hl = lane & 31;       // covers features [hl*8, hl*8+8)
    int s = rowptr[node], e = rowptr[node + 1];
    const short* base = hs + hl * 8;

    float acc[4][8] = {};
    int i = s + half;
    for (; i + 6 < e; i += 8) {
        int n0 = colidx[i], n1 = colidx[i + 2], n2 = colidx[i + 4], n3 = colidx[i + 6];
        uint4 u0 = *(const uint4*)(base + (size_t)n0 * DH);
        uint4 u1 = *(const uint4*)(base + (size_t)n1 * DH);
        uint4 u2 = *(const uint4*)(base + (size_t)n2 * DH);
        uint4 u3 = *(const uint4*)(base + (size_t)n3 * DH);
        acc[0][0] += bf_lo(u0.x); acc[0][1] += bf_hi(u0.x);
        acc[0][2] += bf_lo(u0.y); acc[0][3] += bf_hi(u0.y);
        acc[0][4] += bf_lo(u0.z); acc[0][5] += bf_hi(u0.z);
        acc[0][6] += bf_lo(u0.w); acc[0][7] += bf_hi(u0.w);
        acc[1][0] += bf_lo(u1.x); acc[1][1] += bf_hi(u1.x);
        acc[1][2] += bf_lo(u1.y); acc[1][3] += bf_hi(u1.y);
        acc[1][4] += bf_lo(u1.z); acc[1][5] += bf_hi(u1.z);
        acc[1][6] += bf_lo(u1.w); acc[1][7] += bf_hi(u1.w);
        acc[2][0] += bf_lo(u2.x); acc[2][1] += bf_hi(u2.x);
        acc[2][2] += bf_lo(u2.y); acc[2][3] += bf_hi(u2.y);
        acc[2][4] += bf_lo(u2.z); acc[2][5] += bf_hi(u2.z);
        acc[2][6] += bf_lo(u2.w); acc[2][7] += bf_hi(u2.w);
        acc[3][0] += bf_lo(u3.x); acc[3][1] += bf_hi(u3.x);
        acc[3][2] += bf_lo(u3.y); acc[3][3] += bf_hi(u3.y);
        acc[3][4] += bf_lo(u3.z); acc[3][5] += bf_hi(u3.z);
        acc[3][6] += bf_lo(u3.w); acc[3][7] += bf_hi(u3.w);
    }
    for (; i < e; i += 2) {
        int n = colidx[i];
        uint4 u = *(const uint4*)(base + (size_t)n * DH);
        acc[0][0] += bf_lo(u.x); acc[0][1] += bf_hi(u.x);
        acc[0][2] += bf_lo(u.y); acc[0][3] += bf_hi(u.y);
        acc[0][4] += bf_lo(u.z); acc[0][5] += bf_hi(u.z);
        acc[0][6] += bf_lo(u.w); acc[0][7] += bf_hi(u.w);
    }
    float f[8];
#pragma unroll
    for (int j = 0; j < 8; j++) {
        f[j] = (acc[0][j] + acc[1][j]) + (acc[2][j] + acc[3][j]);
        f[j] += __shfl_xor(f[j], 32);
    }
    if (half == 0) {
        float d = dinv[node];
        short8 r;
#pragma unroll
        for (int j = 0; j < 8; j++) r[j] = f2bf(f[j] * d);
        *(short8*)(out + (size_t)node * DH + hl * 8) = r;
    }
}

// ---------------------------------------------------------------- BN stats (bf16 input)

__global__ __launch_bounds__(256) void k_bnstats(const short* __restrict__ o,
                                                 float* __restrict__ psum,
                                                 float* __restrict__ psq) {
    int col = threadIdx.x;
    float s = 0.f, ss = 0.f;
    for (int r = blockIdx.x; r < N_NODES; r += gridDim.x) {
        float v = bfval(o[(size_t)r * DH + col]);
        s += v;
        ss = fmaf(v, v, ss);
    }
    psum[(size_t)blockIdx.x * DH + col] = s;
    psq[(size_t)blockIdx.x * DH + col] = ss;
}

__global__ __launch_bounds__(256) void k_bnfinal(
    const float* __restrict__ psum, const float* __restrict__ psq,
    const float* __restrict__ gamma, const float* __restrict__ beta,
    float* __restrict__ scale, float* __restrict__ shift) {
    int c = threadIdx.x;
    float s = 0.f, ss = 0.f;
    for (int b = 0; b < STATS_BLOCKS; b++) {
        s += psum[(size_t)b * DH + c];
        ss += psq[(size_t)b * DH + c];
    }
    float mu = s / (float)N_NODES;
    float var = ss / (float)N_NODES - mu * mu;
    float rs = rsqrtf(var + BN_EPS);
    float sc = gamma[c] * rs;
    scale[c] = sc;
    shift[c] = beta[c] - mu * sc;
}

// ---------------------------------------------------------------- final agg + log_softmax

__global__ __launch_bounds__(256) void k_agg_softmax(
    const short* __restrict__ hsl, const int* __restrict__ rowptr,
    const int* __restrict__ colidx, const float* __restrict__ dinv,
    const float* __restrict__ bias, float* __restrict__ out) {
    int gid = blockIdx.x * blockDim.x + threadIdx.x;
    int node = gid >> 6;
    int lane = threadIdx.x & 63;
    if (node >= N_NODES) return;
    int s = rowptr[node], e = rowptr[node + 1];
    float a[8] = {};
    if (lane < DOUTP) {
        const short* base = hsl + lane;
        int i = s;
        for (; i + 8 <= e; i += 8) {
#pragma unroll
            for (int j = 0; j < 8; j++)
                a[j] += bfval(base[(size_t)colidx[i + j] * DOUTP]);
        }
        for (; i < e; i++) a[0] += bfval(base[(size_t)colidx[i] * DOUTP]);
        a[0] = ((a[0] + a[1]) + (a[2] + a[3])) + ((a[4] + a[5]) + (a[6] + a[7]));
    }
    float acc = 0.f;
    if (lane < DOUT) acc = fmaf(a[0], dinv[node], bias[lane]);
    float v = (lane < DOUT) ? acc : -INFINITY;
    float m = v;
#pragma unroll
    for (int off = 32; off; off >>= 1) m = fmaxf(m, __shfl_xor(m, off));
    float ex = (lane < DOUT) ? expf(acc - m) : 0.f;
    float sum = ex;
#pragma unroll
    for (int off = 32; off; off >>= 1) sum += __shfl_xor(sum, off);
    if (lane < DOUT) out[(size_t)node * DOUT + lane] = acc - m - logf(sum);
}

// ---------------------------------------------------------------- launch

static inline size_t align_up(size_t x, size_t a) { return (x + a - 1) & ~(a - 1); }

extern "C" void kernel_launch(void* const* d_in, const int* in_sizes, int n_in,
                              void* d_out, int out_size, void* d_ws, size_t ws_size,
                              hipStream_t stream) {
    const float* x     = (const float*)d_in[0];   // [N, 128]
    const float* W0    = (const float*)d_in[1];   // [128, 256]
    const float* Wh    = (const float*)d_in[3];   // [3, 256, 256]
    const float* gamma = (const float*)d_in[5];   // [4, 256]
    const float* beta  = (const float*)d_in[6];   // [4, 256]
    const float* Wl    = (const float*)d_in[7];   // [256, 40]
    const float* bl    = (const float*)d_in[8];   // [40]
    const int* ei      = (const int*)d_in[9];     // [2, E]
    const int* row = ei;
    const int* col = ei + N_EDGES;
    float* out = (float*)d_out;

    // workspace layout
    char* ws = (char*)d_ws;
    size_t off = 0;
    short* h    = (short*)(ws + off); off = align_up(off + (size_t)N_NODES * DH * 2, 256);
    short* hs   = (short*)(ws + off); off = align_up(off + (size_t)N_NODES * DH * 2, 256);
    short* hsl  = (short*)(ws + off); off = align_up(off + (size_t)N_NODES * DOUTP * 2, 256);
    short* wt0  = (short*)(ws + off); off = align_up(off + (size_t)DH * DIN * 2, 256);
    short* wth  = (short*)(ws + off); off = align_up(off + (size_t)3 * DH * DH * 2, 256);
    short* wtl  = (short*)(ws + off); off = align_up(off + (size_t)DOUTP * DH * 2, 256);
    int* colidx = (int*)(ws + off);  off = align_up(off + (size_t)(N_EDGES + N_NODES) * 4, 256);
    int* cnt    = (int*)(ws + off);  off = align_up(off + (size_t)N_NODES * 4, 256);
    int* fill   = (int*)(ws + off);  off = align_up(off + (size_t)N_NODES * 4, 256);
    int* rowptr = (int*)(ws + off);  off = align_up(off + (size_t)(N_NODES + 1) * 4, 256);
    int* partials = (int*)(ws + off); off = align_up(off + (size_t)SCAN_BLOCKS * 4, 256);
    float* dinv = (float*)(ws + off); off = align_up(off + (size_t)N_NODES * 4, 256);
    float* psum = (float*)(ws + off); off = align_up(off + (size_t)STATS_BLOCKS * DH * 4, 256);
    float* psq  = (float*)(ws + off); off = align_up(off + (size_t)STATS_BLOCKS * DH * 4, 256);
    float* scale = (float*)(ws + off); off = align_up(off + DH * 4, 256);
    float* shift = (float*)(ws + off); off = align_up(off + DH * 4, 256);
    (void)ws_size; (void)n_in; (void)in_sizes; (void)out_size;

    hipMemsetAsync(cnt, 0, (size_t)N_NODES * 4, stream);
    hipMemsetAsync(fill, 0, (size_t)N_NODES * 4, stream);

    const int EB = (N_EDGES + 255) / 256;
    const int NBK = (N_NODES + 255) / 256;
    k_count<<<EB, 256, 0, stream>>>(row, cnt);
    k_scan_a<<<SCAN_BLOCKS, 256, 0, stream>>>(cnt, rowptr, partials, dinv, N_NODES);
    k_scan_b<<<1, 128, 0, stream>>>(partials, rowptr, SCAN_BLOCKS, N_NODES);
    k_scan_c<<<SCAN_BLOCKS, 256, 0, stream>>>(rowptr, partials, N_NODES);
    k_scatter<<<EB, 256, 0, stream>>>(row, col, rowptr, fill, colidx);
    k_selfloop<<<NBK, 256, 0, stream>>>(rowptr, colidx);

    k_prep_w<<<(DIN * DH + 255) / 256, 256, 0, stream>>>(W0, wt0, DIN, DH);
    for (int i = 0; i < 3; i++)
        k_prep_w<<<(DH * DH + 255) / 256, 256, 0, stream>>>(
            Wh + (size_t)i * DH * DH, wth + (size_t)i * DH * DH, DH, DH);
    k_prep_wl<<<(DOUTP * DH + 255) / 256, 256, 0, stream>>>(Wl, wtl, DH);

    const int gemm_blocks = (N_NODES + BM - 1) / BM;
    const int agg_blocks = (N_NODES * 64 + 255) / 256;

    // Layer 0: hs = dinv * (x @ W0), bf16  (conv bias cancels in BN)
    k_gemm_mfma<false, false><<<gemm_blocks, 256, 0, stream>>>(
        x, wt0, hs, dinv, nullptr, nullptr, N_NODES, DIN);
    k_aggregate_bf16<<<agg_blocks, 256, 0, stream>>>(hs, rowptr, colidx, dinv, h);
    k_bnstats<<<STATS_BLOCKS, 256, 0, stream>>>(h, psum, psq);
    k_bnfinal<<<1, 256, 0, stream>>>(psum, psq, gamma, beta, scale, shift);

    // Layers 1..3
    for (int i = 0; i < 3; i++) {
        k_gemm_mfma<true, true><<<gemm_blocks, 256, 0, stream>>>(
            h, wth + (size_t)i * DH * DH, hs, dinv, scale, shift, N_NODES, DH);
        k_aggregate_bf16<<<agg_blocks, 256, 0, stream>>>(hs, rowptr, colidx, dinv, h);
        k_bnstats<<<STATS_BLOCKS, 256, 0, stream>>>(h, psum, psq);
        k_bnfinal<<<1, 256, 0, stream>>>(psum, psq, gamma + (size_t)(i + 1) * DH,
                                         beta + (size_t)(i + 1) * DH, scale, shift);
    }

    // Layer 4: MFMA -> DOUTP bf16, then fused aggregate + bias + log_softmax
    k_gemm_last<<<gemm_blocks, 256, 0, stream>>>(h, wtl, hsl, dinv, scale, shift, N_NODES);
    k_agg_softmax<<<agg_blocks, 256, 0, stream>>>(hsl, rowptr, colidx, dinv, bl, out);
}

// Round 6
// 1059.714 us; speedup vs baseline: 2.8444x; 1.2503x over previous
//
#include <hip/hip_runtime.h>
#include <hip/hip_bf16.h>
#include <math.h>
#include <stdint.h>

#define N_NODES 100000
#define N_EDGES 1600000
#define DIN 128
#define DH 256
#define DOUT 40
#define DOUTP 48
#define BN_EPS 1e-5f
#define SCAN_BLOCKS ((N_NODES + 1023) / 1024)   // 98

// bucketed CSR build
#define RPB 512                                  // rows per bucket
#define NBKT ((N_NODES + RPB - 1) / RPB)         // 196
#define BCAP 10240                               // per-bucket capacity (mean 8192)
#define EPB 8192                                 // edges per k_bucket block

#define AGG_GRID 1024                            // persistent aggregate blocks

typedef __attribute__((ext_vector_type(8))) short short8;
typedef __attribute__((ext_vector_type(4))) short short4v;
typedef __attribute__((ext_vector_type(4))) float floatx4;

__device__ __forceinline__ short f2bf(float f) {
    uint32_t u = __float_as_uint(f);
    uint32_t r = u + 0x7FFF + ((u >> 16) & 1);   // RNE
    return (short)(r >> 16);
}
__device__ __forceinline__ float bf_lo(uint32_t u) { return __uint_as_float(u << 16); }
__device__ __forceinline__ float bf_hi(uint32_t u) { return __uint_as_float(u & 0xFFFF0000u); }
__device__ __forceinline__ float bfval(short s) {
    return __uint_as_float(((uint32_t)(unsigned short)s) << 16);
}

// ---------------------------------------------------------------- CSR build
// Pass 1: count degrees + bin edges into 196 row-range buckets.
// LDS assigns within-block positions; one global reservation per bucket/block
// -> bucket appends are ~340B contiguous runs (full-line writebacks).

__global__ __launch_bounds__(256) void k_bucket(
    const int* __restrict__ row, const int* __restrict__ col,
    int* __restrict__ cnt, int* __restrict__ bcnt, int2* __restrict__ bkt) {
    __shared__ int lcnt[NBKT];
    __shared__ int gbase[NBKT];
    __shared__ unsigned short parr[EPB];
    const int t = threadIdx.x;
    const int e0 = blockIdx.x * EPB;
    for (int i = t; i < NBKT; i += 256) lcnt[i] = 0;
    __syncthreads();
    for (int i = t; i < EPB; i += 256) {
        int e = e0 + i;
        if (e < N_EDGES) {
            int r = row[e];
            atomicAdd(&cnt[r], 1);
            int b = r >> 9;                       // RPB = 512
            parr[i] = (unsigned short)atomicAdd(&lcnt[b], 1);
        }
    }
    __syncthreads();
    for (int i = t; i < NBKT; i += 256)
        gbase[i] = atomicAdd(&bcnt[i], lcnt[i]);
    __syncthreads();
    for (int i = t; i < EPB; i += 256) {
        int e = e0 + i;
        if (e < N_EDGES) {
            int r = row[e];
            int c = col[e];
            int b = r >> 9;
            int pos = gbase[b] + (int)parr[i];
            if (pos < BCAP) bkt[(size_t)b * BCAP + pos] = make_int2(r, c);
        }
    }
}

__global__ __launch_bounds__(256) void k_scan_a(const int* __restrict__ cnt,
                                                int* __restrict__ rowptr,
                                                int* __restrict__ partials,
                                                float* __restrict__ dinv, int n) {
    int t = threadIdx.x;
    int idx = blockIdx.x * 1024 + t * 4;
    int a0 = 0, a1 = 0, a2 = 0, a3 = 0;
    if (idx + 3 < n) {
        int4 v = *(const int4*)(cnt + idx);
        a0 = v.x + 1; a1 = v.y + 1; a2 = v.z + 1; a3 = v.w + 1;
    } else {
        if (idx + 0 < n) a0 = cnt[idx + 0] + 1;
        if (idx + 1 < n) a1 = cnt[idx + 1] + 1;
        if (idx + 2 < n) a2 = cnt[idx + 2] + 1;
        if (idx + 3 < n) a3 = cnt[idx + 3] + 1;
    }
    if (idx + 0 < n) dinv[idx + 0] = rsqrtf((float)a0);
    if (idx + 1 < n) dinv[idx + 1] = rsqrtf((float)a1);
    if (idx + 2 < n) dinv[idx + 2] = rsqrtf((float)a2);
    if (idx + 3 < n) dinv[idx + 3] = rsqrtf((float)a3);
    int tsum = a0 + a1 + a2 + a3;
    int lane = t & 63, wid = t >> 6;
    int incl = tsum;
#pragma unroll
    for (int off = 1; off < 64; off <<= 1) {
        int x = __shfl_up(incl, off);
        if (lane >= off) incl += x;
    }
    __shared__ int wsum[4];
    if (lane == 63) wsum[wid] = incl;
    __syncthreads();
    int woff = 0;
    for (int i = 0; i < wid; i++) woff += wsum[i];
    int excl = woff + incl - tsum;
    if (idx + 0 < n) rowptr[idx + 0] = excl;
    if (idx + 1 < n) rowptr[idx + 1] = excl + a0;
    if (idx + 2 < n) rowptr[idx + 2] = excl + a0 + a1;
    if (idx + 3 < n) rowptr[idx + 3] = excl + a0 + a1 + a2;
    if (t == 255) partials[blockIdx.x] = woff + incl;
}

__global__ __launch_bounds__(128) void k_scan_b(int* __restrict__ partials,
                                                int* __restrict__ rowptr,
                                                int nb, int n) {
    int t = threadIdx.x;
    int v = (t < nb) ? partials[t] : 0;
    int lane = t & 63, wid = t >> 6;
    int incl = v;
#pragma unroll
    for (int off = 1; off < 64; off <<= 1) {
        int x = __shfl_up(incl, off);
        if (lane >= off) incl += x;
    }
    __shared__ int ws[2];
    if (lane == 63) ws[wid] = incl;
    __syncthreads();
    int woff = (wid == 1) ? ws[0] : 0;
    int excl = woff + incl - v;
    if (t < nb) partials[t] = excl;
    if (t == nb - 1) rowptr[n] = excl + v;
}

__global__ __launch_bounds__(256) void k_scan_c(int* __restrict__ rowptr,
                                                const int* __restrict__ partials, int n) {
    int off = partials[blockIdx.x];
    if (off == 0) return;
    int idx = blockIdx.x * 1024 + threadIdx.x * 4;
    if (idx + 3 < n) {
        int4 v = *(const int4*)(rowptr + idx);
        v.x += off; v.y += off; v.z += off; v.w += off;
        *(int4*)(rowptr + idx) = v;
    } else {
        for (int i = 0; i < 4; i++)
            if (idx + i < n) rowptr[idx + i] += off;
    }
}

// Pass 2: one block per bucket; scatter within the bucket's ~66KB colidx span
// (single-XCD L2-resident). LDS fill counters; self-loops folded in.

__global__ __launch_bounds__(256) void k_fillcsr(
    const int* __restrict__ bcnt, const int2* __restrict__ bkt,
    const int* __restrict__ rowptr, int* __restrict__ colidx) {
    __shared__ int lfill[RPB];
    const int b = blockIdx.x, t = threadIdx.x;
    const int base_row = b * RPB;
    for (int i = t; i < RPB; i += 256) lfill[i] = 0;
    __syncthreads();
    int n = bcnt[b]; if (n > BCAP) n = BCAP;
    const int2* bp = bkt + (size_t)b * BCAP;
    for (int i = t; i < n; i += 256) {
        int2 rc = bp[i];
        int p = atomicAdd(&lfill[rc.x - base_row], 1);
        colidx[rowptr[rc.x] + p] = rc.y;
    }
    __syncthreads();
    for (int i = t; i < RPB; i += 256) {
        int r = base_row + i;
        if (r < N_NODES) colidx[rowptr[r + 1] - 1] = r;
    }
}

// ---------------------------------------------------------------- weight prep (single launch)

__global__ void k_prep_all(const float* __restrict__ W0, const float* __restrict__ Wh,
                           const float* __restrict__ Wl, short* __restrict__ wt0,
                           short* __restrict__ wth, short* __restrict__ wtl) {
    int idx = blockIdx.x * blockDim.x + threadIdx.x;
    if (idx < DH * DIN) {
        int n = idx / DIN, k = idx - n * DIN;
        wt0[idx] = f2bf(W0[(size_t)k * DH + n]);
        return;
    }
    idx -= DH * DIN;
    if (idx < 3 * DH * DH) {
        int m = idx / (DH * DH);
        int r = idx - m * (DH * DH);
        int n = r / DH, k = r - n * DH;
        wth[idx] = f2bf(Wh[(size_t)m * DH * DH + (size_t)k * DH + n]);
        return;
    }
    idx -= 3 * DH * DH;
    if (idx < DOUTP * DH) {
        int n = idx / DH, k = idx - n * DH;
        wtl[idx] = (n < DOUT) ? f2bf(Wl[(size_t)k * DOUT + n]) : (short)0;
    }
}

// ---------------------------------------------------------------- MFMA GEMM
// C_bf16[m][n] = dinv[m] * sum_k act(A[m][k]) * W[k][n],  n = 0..255

#define BM 64
#define BN_T 256
#define BK 64
#define BKP 72

template <bool ABF16, bool BN_ACT>
__global__ __launch_bounds__(256) void k_gemm_mfma(
    const void* __restrict__ Ap, const short* __restrict__ Wt,
    short* __restrict__ Chs, const float* __restrict__ dinv,
    const float* __restrict__ scale, const float* __restrict__ shift,
    int M, int K) {
    __shared__ __align__(16) short Als[BM * BKP];
    __shared__ __align__(16) short Bls[BN_T * BKP];
    const int t = threadIdx.x;
    const int bm = blockIdx.x * BM;
    const int w = t >> 6, lane = t & 63;
    const int wm = w & 1, wn = w >> 1;
    const int l15 = lane & 15, quad = lane >> 4;

    floatx4 acc[2][8] = {};

    for (int k0 = 0; k0 < K; k0 += BK) {
        {
            int r = t >> 2;
            int c = t & 3;
            int gr = bm + r; if (gr >= M) gr = M - 1;
            short* lp = Als + r * BKP + c * 16;
            if (ABF16) {
                const short* ap = (const short*)Ap + (size_t)gr * K + k0 + c * 16;
                short8 s0 = *(const short8*)(ap);
                short8 s1 = *(const short8*)(ap + 8);
                if (BN_ACT) {
#pragma unroll
                    for (int i = 0; i < 2; i++) {
                        float4 sc = *(const float4*)(scale + k0 + c * 16 + i * 8);
                        float4 sc2 = *(const float4*)(scale + k0 + c * 16 + i * 8 + 4);
                        float4 sh = *(const float4*)(shift + k0 + c * 16 + i * 8);
                        float4 sh2 = *(const float4*)(shift + k0 + c * 16 + i * 8 + 4);
                        short8& s = i ? s1 : s0;
                        short8 o;
                        o[0] = f2bf(fmaxf(fmaf(bfval(s[0]), sc.x, sh.x), 0.f));
                        o[1] = f2bf(fmaxf(fmaf(bfval(s[1]), sc.y, sh.y), 0.f));
                        o[2] = f2bf(fmaxf(fmaf(bfval(s[2]), sc.z, sh.z), 0.f));
                        o[3] = f2bf(fmaxf(fmaf(bfval(s[3]), sc.w, sh.w), 0.f));
                        o[4] = f2bf(fmaxf(fmaf(bfval(s[4]), sc2.x, sh2.x), 0.f));
                        o[5] = f2bf(fmaxf(fmaf(bfval(s[5]), sc2.y, sh2.y), 0.f));
                        o[6] = f2bf(fmaxf(fmaf(bfval(s[6]), sc2.z, sh2.z), 0.f));
                        o[7] = f2bf(fmaxf(fmaf(bfval(s[7]), sc2.w, sh2.w), 0.f));
                        *(short8*)(lp + i * 8) = o;
                    }
                } else {
                    *(short8*)(lp) = s0;
                    *(short8*)(lp + 8) = s1;
                }
            } else {
                const float* ap = (const float*)Ap + (size_t)gr * K + k0 + c * 16;
#pragma unroll
                for (int i = 0; i < 4; i++) {
                    float4 v = *(const float4*)(ap + i * 4);
                    short4v s;
                    s.x = f2bf(v.x); s.y = f2bf(v.y); s.z = f2bf(v.z); s.w = f2bf(v.w);
                    *(short4v*)(lp + i * 4) = s;
                }
            }
        }
        {
            int r0 = t >> 2;
            int c = t & 3;
#pragma unroll
            for (int p = 0; p < 4; p++) {
                int r = r0 + p * 64;
                const short* bp = Wt + (size_t)r * K + k0 + c * 16;
                short* lp = Bls + r * BKP + c * 16;
                *(short8*)(lp) = *(const short8*)(bp);
                *(short8*)(lp + 8) = *(const short8*)(bp + 8);
            }
        }
        __syncthreads();
#pragma unroll
        for (int kc = 0; kc < 2; kc++) {
            short8 af[2], bfr[8];
#pragma unroll
            for (int mi = 0; mi < 2; mi++)
                af[mi] = *(const short8*)(Als + (wm * 32 + mi * 16 + l15) * BKP + kc * 32 + quad * 8);
#pragma unroll
            for (int ni = 0; ni < 8; ni++)
                bfr[ni] = *(const short8*)(Bls + (wn * 128 + ni * 16 + l15) * BKP + kc * 32 + quad * 8);
#pragma unroll
            for (int mi = 0; mi < 2; mi++)
#pragma unroll
                for (int ni = 0; ni < 8; ni++)
                    acc[mi][ni] = __builtin_amdgcn_mfma_f32_16x16x32_bf16(
                        af[mi], bfr[ni], acc[mi][ni], 0, 0, 0);
        }
        __syncthreads();
    }

#pragma unroll
    for (int mi = 0; mi < 2; mi++) {
#pragma unroll
        for (int r = 0; r < 4; r++) {
            int m = bm + wm * 32 + mi * 16 + quad * 4 + r;
            if (m < M) {
                float d = dinv[m];
                size_t base = (size_t)m * BN_T + wn * 128 + l15;
#pragma unroll
                for (int ni = 0; ni < 8; ni++)
                    Chs[base + ni * 16] = f2bf(acc[mi][ni][r] * d);
            }
        }
    }
}

// ---------------------------------------------------------------- MFMA GEMM, final layer

__global__ __launch_bounds__(256) void k_gemm_last(
    const short* __restrict__ A, const short* __restrict__ Wt,
    short* __restrict__ C, const float* __restrict__ dinv,
    const float* __restrict__ scale, const float* __restrict__ shift, int M) {
    __shared__ __align__(16) short Als[BM * BKP];
    __shared__ __align__(16) short Bls[DOUTP * BKP];
    const int t = threadIdx.x;
    const int bm = blockIdx.x * BM;
    const int w = t >> 6, lane = t & 63;
    const int l15 = lane & 15, quad = lane >> 4;
    const int K = DH;

    floatx4 acc[3] = {};

    for (int k0 = 0; k0 < K; k0 += BK) {
        {
            int r = t >> 2;
            int c = t & 3;
            int gr = bm + r; if (gr >= M) gr = M - 1;
            const short* ap = A + (size_t)gr * K + k0 + c * 16;
            short* lp = Als + r * BKP + c * 16;
            short8 s0 = *(const short8*)(ap);
            short8 s1 = *(const short8*)(ap + 8);
#pragma unroll
            for (int i = 0; i < 2; i++) {
                float4 sc = *(const float4*)(scale + k0 + c * 16 + i * 8);
                float4 sc2 = *(const float4*)(scale + k0 + c * 16 + i * 8 + 4);
                float4 sh = *(const float4*)(shift + k0 + c * 16 + i * 8);
                float4 sh2 = *(const float4*)(shift + k0 + c * 16 + i * 8 + 4);
                short8& s = i ? s1 : s0;
                short8 o;
                o[0] = f2bf(fmaxf(fmaf(bfval(s[0]), sc.x, sh.x), 0.f));
                o[1] = f2bf(fmaxf(fmaf(bfval(s[1]), sc.y, sh.y), 0.f));
                o[2] = f2bf(fmaxf(fmaf(bfval(s[2]), sc.z, sh.z), 0.f));
                o[3] = f2bf(fmaxf(fmaf(bfval(s[3]), sc.w, sh.w), 0.f));
                o[4] = f2bf(fmaxf(fmaf(bfval(s[4]), sc2.x, sh2.x), 0.f));
                o[5] = f2bf(fmaxf(fmaf(bfval(s[5]), sc2.y, sh2.y), 0.f));
                o[6] = f2bf(fmaxf(fmaf(bfval(s[6]), sc2.z, sh2.z), 0.f));
                o[7] = f2bf(fmaxf(fmaf(bfval(s[7]), sc2.w, sh2.w), 0.f));
                *(short8*)(lp + i * 8) = o;
            }
        }
        if (t < 192) {
            int r = t >> 2;
            int c = t & 3;
            const short* bp = Wt + (size_t)r * K + k0 + c * 16;
            short* lp = Bls + r * BKP + c * 16;
            *(short8*)(lp) = *(const short8*)(bp);
            *(short8*)(lp + 8) = *(const short8*)(bp + 8);
        }
        __syncthreads();
#pragma unroll
        for (int kc = 0; kc < 2; kc++) {
            short8 af = *(const short8*)(Als + (w * 16 + l15) * BKP + kc * 32 + quad * 8);
#pragma unroll
            for (int ni = 0; ni < 3; ni++) {
                short8 bfr = *(const short8*)(Bls + (ni * 16 + l15) * BKP + kc * 32 + quad * 8);
                acc[ni] = __builtin_amdgcn_mfma_f32_16x16x32_bf16(af, bfr, acc[ni], 0, 0, 0);
            }
        }
        __syncthreads();
    }

#pragma unroll
    for (int r = 0; r < 4; r++) {
        int m = bm + w * 16 + quad * 4 + r;
        if (m >= M) continue;
        float d = dinv[m];
#pragma unroll
        for (int ni = 0; ni < 3; ni++)
            C[(size_t)m * DOUTP + ni * 16 + l15] = f2bf(acc[ni][r] * d);
    }
}

// ---------------------------------------------------------------- aggregation + fused BN stats
// Persistent grid (AGG_GRID blocks, 4 waves = 4 nodes/iter). Half-wave uint4
// gather (8 neighbors in flight). Per-thread register sum/sumsq accumulators,
// block-level LDS reduce, one atomicAdd per feature per block.

__global__ __launch_bounds__(256) void k_aggregate_bf16(
    const short* __restrict__ hs, const int* __restrict__ rowptr,
    const int* __restrict__ colidx, const float* __restrict__ dinv,
    short* __restrict__ out, float* __restrict__ psum, float* __restrict__ psq) {
    __shared__ float lps[4][DH];
    __shared__ float lpq[4][DH];
    const int w = threadIdx.x >> 6;
    const int lane = threadIdx.x & 63;
    const int half = lane >> 5;
    const int hl = lane & 31;
    const short* base = hs + hl * 8;

    float stat_s[8] = {};
    float stat_q[8] = {};

    for (int node = blockIdx.x * 4 + w; node < N_NODES; node += AGG_GRID * 4) {
        int s = rowptr[node], e = rowptr[node + 1];
        float acc[4][8] = {};
        int i = s + half;
        for (; i + 6 < e; i += 8) {
            int n0 = colidx[i], n1 = colidx[i + 2], n2 = colidx[i + 4], n3 = colidx[i + 6];
            uint4 u0 = *(const uint4*)(base + (size_t)n0 * DH);
            uint4 u1 = *(const uint4*)(base + (size_t)n1 * DH);
            uint4 u2 = *(const uint4*)(base + (size_t)n2 * DH);
            uint4 u3 = *(const uint4*)(base + (size_t)n3 * DH);
            acc[0][0] += bf_lo(u0.x); acc[0][1] += bf_hi(u0.x);
            acc[0][2] += bf_lo(u0.y); acc[0][3] += bf_hi(u0.y);
            acc[0][4] += bf_lo(u0.z); acc[0][5] += bf_hi(u0.z);
            acc[0][6] += bf_lo(u0.w); acc[0][7] += bf_hi(u0.w);
            acc[1][0] += bf_lo(u1.x); acc[1][1] += bf_hi(u1.x);
            acc[1][2] += bf_lo(u1.y); acc[1][3] += bf_hi(u1.y);
            acc[1][4] += bf_lo(u1.z); acc[1][5] += bf_hi(u1.z);
            acc[1][6] += bf_lo(u1.w); acc[1][7] += bf_hi(u1.w);
            acc[2][0] += bf_lo(u2.x); acc[2][1] += bf_hi(u2.x);
            acc[2][2] += bf_lo(u2.y); acc[2][3] += bf_hi(u2.y);
            acc[2][4] += bf_lo(u2.z); acc[2][5] += bf_hi(u2.z);
            acc[2][6] += bf_lo(u2.w); acc[2][7] += bf_hi(u2.w);
            acc[3][0] += bf_lo(u3.x); acc[3][1] += bf_hi(u3.x);
            acc[3][2] += bf_lo(u3.y); acc[3][3] += bf_hi(u3.y);
            acc[3][4] += bf_lo(u3.z); acc[3][5] += bf_hi(u3.z);
            acc[3][6] += bf_lo(u3.w); acc[3][7] += bf_hi(u3.w);
        }
        for (; i < e; i += 2) {
            int n = colidx[i];
            uint4 u = *(const uint4*)(base + (size_t)n * DH);
            acc[0][0] += bf_lo(u.x); acc[0][1] += bf_hi(u.x);
            acc[0][2] += bf_lo(u.y); acc[0][3] += bf_hi(u.y);
            acc[0][4] += bf_lo(u.z); acc[0][5] += bf_hi(u.z);
            acc[0][6] += bf_lo(u.w); acc[0][7] += bf_hi(u.w);
        }
        float d = dinv[node];
        float f[8];
#pragma unroll
        for (int j = 0; j < 8; j++) {
            f[j] = (acc[0][j] + acc[1][j]) + (acc[2][j] + acc[3][j]);
            f[j] += __shfl_xor(f[j], 32);
            f[j] *= d;
        }
        if (half == 0) {
            short8 r;
#pragma unroll
            for (int j = 0; j < 8; j++) {
                r[j] = f2bf(f[j]);
                stat_s[j] += f[j];
                stat_q[j] = fmaf(f[j], f[j], stat_q[j]);
            }
            *(short8*)(out + (size_t)node * DH + hl * 8) = r;
        }
    }

    if (half == 0) {
#pragma unroll
        for (int j = 0; j < 8; j++) {
            lps[w][hl * 8 + j] = stat_s[j];
            lpq[w][hl * 8 + j] = stat_q[j];
        }
    }
    __syncthreads();
    int c = threadIdx.x;
    float S = (lps[0][c] + lps[1][c]) + (lps[2][c] + lps[3][c]);
    float Q = (lpq[0][c] + lpq[1][c]) + (lpq[2][c] + lpq[3][c]);
    atomicAdd(&psum[c], S);
    atomicAdd(&psq[c], Q);
}

// ---------------------------------------------------------------- BN finalize

__global__ void k_bnfinal(const float* __restrict__ psum, const float* __restrict__ psq,
                          const float* __restrict__ gamma, const float* __restrict__ beta,
                          float* __restrict__ scale, float* __restrict__ shift) {
    int c = threadIdx.x;
    float mu = psum[c] / (float)N_NODES;
    float var = psq[c] / (float)N_NODES - mu * mu;
    float rs = rsqrtf(var + BN_EPS);
    float sc = gamma[c] * rs;
    scale[c] = sc;
    shift[c] = beta[c] - mu * sc;
}

// ---------------------------------------------------------------- final agg + log_softmax

__global__ __launch_bounds__(256) void k_agg_softmax(
    const short* __restrict__ hsl, const int* __restrict__ rowptr,
    const int* __restrict__ colidx, const float* __restrict__ dinv,
    const float* __restrict__ bias, float* __restrict__ out) {
    int gid = blockIdx.x * blockDim.x + threadIdx.x;
    int node = gid >> 6;
    int lane = threadIdx.x & 63;
    if (node >= N_NODES) return;
    int s = rowptr[node], e = rowptr[node + 1];
    float a[8] = {};
    if (lane < DOUTP) {
        const short* base = hsl + lane;
        int i = s;
        for (; i + 8 <= e; i += 8) {
#pragma unroll
            for (int j = 0; j < 8; j++)
                a[j] += bfval(base[(size_t)colidx[i + j] * DOUTP]);
        }
        for (; i < e; i++) a[0] += bfval(base[(size_t)colidx[i] * DOUTP]);
        a[0] = ((a[0] + a[1]) + (a[2] + a[3])) + ((a[4] + a[5]) + (a[6] + a[7]));
    }
    float acc = 0.f;
    if (lane < DOUT) acc = fmaf(a[0], dinv[node], bias[lane]);
    float v = (lane < DOUT) ? acc : -INFINITY;
    float m = v;
#pragma unroll
    for (int off = 32; off; off >>= 1) m = fmaxf(m, __shfl_xor(m, off));
    float ex = (lane < DOUT) ? expf(acc - m) : 0.f;
    float sum = ex;
#pragma unroll
    for (int off = 32; off; off >>= 1) sum += __shfl_xor(sum, off);
    if (lane < DOUT) out[(size_t)node * DOUT + lane] = acc - m - logf(sum);
}

// ---------------------------------------------------------------- launch

static inline size_t align_up(size_t x, size_t a) { return (x + a - 1) & ~(a - 1); }

extern "C" void kernel_launch(void* const* d_in, const int* in_sizes, int n_in,
                              void* d_out, int out_size, void* d_ws, size_t ws_size,
                              hipStream_t stream) {
    const float* x     = (const float*)d_in[0];   // [N, 128]
    const float* W0    = (const float*)d_in[1];   // [128, 256]
    const float* Wh    = (const float*)d_in[3];   // [3, 256, 256]
    const float* gamma = (const float*)d_in[5];   // [4, 256]
    const float* beta  = (const float*)d_in[6];   // [4, 256]
    const float* Wl    = (const float*)d_in[7];   // [256, 40]
    const float* bl    = (const float*)d_in[8];   // [40]
    const int* ei      = (const int*)d_in[9];     // [2, E]
    const int* row = ei;
    const int* col = ei + N_EDGES;
    float* out = (float*)d_out;

    // workspace layout
    char* ws = (char*)d_ws;
    size_t off = 0;
    short* h    = (short*)(ws + off); off = align_up(off + (size_t)N_NODES * DH * 2, 256);
    short* hs   = (short*)(ws + off); off = align_up(off + (size_t)N_NODES * DH * 2, 256);
    short* hsl  = (short*)(ws + off); off = align_up(off + (size_t)N_NODES * DOUTP * 2, 256);
    short* wt0  = (short*)(ws + off); off = align_up(off + (size_t)DH * DIN * 2, 256);
    short* wth  = (short*)(ws + off); off = align_up(off + (size_t)3 * DH * DH * 2, 256);
    short* wtl  = (short*)(ws + off); off = align_up(off + (size_t)DOUTP * DH * 2, 256);
    int* colidx = (int*)(ws + off);  off = align_up(off + (size_t)(N_EDGES + N_NODES) * 4, 256);
    int2* bkt   = (int2*)(ws + off); off = align_up(off + (size_t)NBKT * BCAP * 8, 256);
    int* rowptr = (int*)(ws + off);  off = align_up(off + (size_t)(N_NODES + 1) * 4, 256);
    int* partials = (int*)(ws + off); off = align_up(off + (size_t)SCAN_BLOCKS * 4, 256);
    float* dinv = (float*)(ws + off); off = align_up(off + (size_t)N_NODES * 4, 256);
    float* scale = (float*)(ws + off); off = align_up(off + DH * 4, 256);
    float* shift = (float*)(ws + off); off = align_up(off + DH * 4, 256);
    // zero-init region (single memset): cnt, bcnt, psum[4][256], psq[4][256]
    size_t zero_begin = off;
    int* cnt    = (int*)(ws + off);  off = align_up(off + (size_t)N_NODES * 4, 256);
    int* bcnt   = (int*)(ws + off);  off = align_up(off + (size_t)NBKT * 4, 256);
    float* psum = (float*)(ws + off); off = align_up(off + (size_t)4 * DH * 4, 256);
    float* psq  = (float*)(ws + off); off = align_up(off + (size_t)4 * DH * 4, 256);
    size_t zero_end = off;
    (void)ws_size; (void)n_in; (void)in_sizes; (void)out_size;

    hipMemsetAsync(ws + zero_begin, 0, zero_end - zero_begin, stream);

    // CSR build
    const int BKT_BLOCKS = (N_EDGES + EPB - 1) / EPB;   // 196
    k_bucket<<<BKT_BLOCKS, 256, 0, stream>>>(row, col, cnt, bcnt, bkt);
    k_scan_a<<<SCAN_BLOCKS, 256, 0, stream>>>(cnt, rowptr, partials, dinv, N_NODES);
    k_scan_b<<<1, 128, 0, stream>>>(partials, rowptr, SCAN_BLOCKS, N_NODES);
    k_scan_c<<<SCAN_BLOCKS, 256, 0, stream>>>(rowptr, partials, N_NODES);
    k_fillcsr<<<NBKT, 256, 0, stream>>>(bcnt, bkt, rowptr, colidx);

    // weight prep
    const int PREP_N = DH * DIN + 3 * DH * DH + DOUTP * DH;
    k_prep_all<<<(PREP_N + 255) / 256, 256, 0, stream>>>(W0, Wh, Wl, wt0, wth, wtl);

    const int gemm_blocks = (N_NODES + BM - 1) / BM;
    const int agg_blocks = (N_NODES * 64 + 255) / 256;

    // Layer 0: hs = dinv * (x @ W0) (conv bias cancels in training-mode BN)
    k_gemm_mfma<false, false><<<gemm_blocks, 256, 0, stream>>>(
        x, wt0, hs, dinv, nullptr, nullptr, N_NODES, DIN);
    k_aggregate_bf16<<<AGG_GRID, 256, 0, stream>>>(hs, rowptr, colidx, dinv, h,
                                                   psum, psq);
    k_bnfinal<<<1, 256, 0, stream>>>(psum, psq, gamma, beta, scale, shift);

    // Layers 1..3
    for (int i = 0; i < 3; i++) {
        k_gemm_mfma<true, true><<<gemm_blocks, 256, 0, stream>>>(
            h, wth + (size_t)i * DH * DH, hs, dinv, scale, shift, N_NODES, DH);
        k_aggregate_bf16<<<AGG_GRID, 256, 0, stream>>>(hs, rowptr, colidx, dinv, h,
                                                       psum + (i + 1) * DH,
                                                       psq + (i + 1) * DH);
        k_bnfinal<<<1, 256, 0, stream>>>(psum + (i + 1) * DH, psq + (i + 1) * DH,
                                         gamma + (size_t)(i + 1) * DH,
                                         beta + (size_t)(i + 1) * DH, scale, shift);
    }

    // Layer 4: MFMA -> DOUTP bf16, then fused aggregate + bias + log_softmax
    k_gemm_last<<<gemm_blocks, 256, 0, stream>>>(h, wtl, hsl, dinv, scale, shift, N_NODES);
    k_agg_softmax<<<agg_blocks, 256, 0, stream>>>(hsl, rowptr, colidx, dinv, bl, out);
}